// Round 1
// baseline (756.242 us; speedup 1.0000x reference)
//
#include <hip/hip_runtime.h>

// ---------------------------------------------------------------------------
// 3-layer GCN: out = GCNConv3( relu(GCNConv2( relu(GCNConv1(x)) )) )
// GCNConv(h) = D^{-1/2} (A + I) D^{-1/2} (h W) + b, deg from dst (+self loop)
// Strategy: build CSR (by dst) once per call, fp32 tiled GEMM (no fp32 MFMA
// on CDNA4), gather-based aggregation (no float atomics -> deterministic up
// to CSR slot order, ~1e-7 relative).
// ---------------------------------------------------------------------------

__global__ void count_kernel(const int* __restrict__ dst, int* __restrict__ cnt, int E) {
    int i = blockIdx.x * blockDim.x + threadIdx.x;
    if (i < E) atomicAdd(&cnt[dst[i]], 1);
}

__global__ void dinv_kernel(const int* __restrict__ cnt, float* __restrict__ dinv, int n) {
    int i = blockIdx.x * blockDim.x + threadIdx.x;
    if (i < n) dinv[i] = rsqrtf((float)(cnt[i] + 1));  // +1 self loop; always > 0
}

// Single-block exclusive scan of cnt[0..n) -> row_ptr[0..n]; row_ptr[n] = total.
__global__ __launch_bounds__(1024) void scan_kernel(const int* __restrict__ cnt,
                                                    int* __restrict__ row_ptr, int n) {
    __shared__ int wsum[16];
    __shared__ int chunk_total;
    const int VPT = 8;
    const int CHUNK = 1024 * VPT;
    int tid = threadIdx.x;
    int lane = tid & 63;
    int wid = tid >> 6;
    int running = 0;
    for (int base = 0; base < n; base += CHUNK) {
        int idx0 = base + tid * VPT;
        int v[VPT];
        int tsum = 0;
#pragma unroll
        for (int j = 0; j < VPT; ++j) {
            int i = idx0 + j;
            v[j] = (i < n) ? cnt[i] : 0;
            tsum += v[j];
        }
        // wave-64 inclusive scan of per-thread sums
        int x = tsum;
#pragma unroll
        for (int off = 1; off < 64; off <<= 1) {
            int y = __shfl_up(x, off);
            if (lane >= off) x += y;
        }
        if (lane == 63) wsum[wid] = x;
        __syncthreads();
        if (wid == 0) {
            int ws = (lane < 16) ? wsum[lane] : 0;
#pragma unroll
            for (int off = 1; off < 16; off <<= 1) {
                int y = __shfl_up(ws, off);
                if (lane >= off) ws += y;
            }
            if (lane < 16) wsum[lane] = ws;
            if (lane == 15) chunk_total = ws;
        }
        __syncthreads();
        int woff = (wid > 0) ? wsum[wid - 1] : 0;
        int excl = running + woff + (x - tsum);
#pragma unroll
        for (int j = 0; j < VPT; ++j) {
            int i = idx0 + j;
            if (i < n) row_ptr[i] = excl;
            excl += v[j];
        }
        running += chunk_total;
        __syncthreads();  // protect wsum reuse next chunk
    }
    if (tid == 0) row_ptr[n] = running;
}

__global__ void scatter_kernel(const int* __restrict__ src, const int* __restrict__ dst,
                               const int* __restrict__ row_ptr, int* __restrict__ cursor,
                               int* __restrict__ csr_src, int E) {
    int i = blockIdx.x * blockDim.x + threadIdx.x;
    if (i < E) {
        int d = dst[i];
        int pos = row_ptr[d] + atomicAdd(&cursor[d], 1);
        csr_src[pos] = src[i];
    }
}

// fp32 GEMM: H[n_rows][n_out] = X[n_rows][128] * W[128][n_out].
// BM=BN=BK=64, 256 threads, 4x4 microtile, A stored transposed in LDS so
// both fragments load as float4 (ds_read_b128).
__global__ __launch_bounds__(256) void gemm_kernel(const float* __restrict__ X,
                                                   const float* __restrict__ W,
                                                   float* __restrict__ H,
                                                   int n_rows, int n_out) {
    __shared__ float As[64][68];  // As[k][m] (transposed), pad 4 to break bank conflicts
    __shared__ float Bs[64][68];  // Bs[k][n]
    int tid = threadIdx.x;
    int tx = tid & 15;   // col group 0..15
    int ty = tid >> 4;   // row group 0..15
    int row0 = blockIdx.x * 64;
    int col0 = blockIdx.y * 64;
    float4 acc[4];
#pragma unroll
    for (int i = 0; i < 4; ++i) acc[i] = make_float4(0.f, 0.f, 0.f, 0.f);

    for (int k0 = 0; k0 < 128; k0 += 64) {
        // A tile: rows row0..+63, K k0..+63 (X stride fixed 128)
#pragma unroll
        for (int p = 0; p < 4; ++p) {
            int r = (tid >> 4) + p * 16;
            int grow = row0 + r;
            int kk = tx * 4;
            float4 a = make_float4(0.f, 0.f, 0.f, 0.f);
            if (grow < n_rows) a = *(const float4*)(X + (size_t)grow * 128 + k0 + kk);
            As[kk + 0][r] = a.x;
            As[kk + 1][r] = a.y;
            As[kk + 2][r] = a.z;
            As[kk + 3][r] = a.w;
        }
        // B tile: W rows k0..+63, cols col0..+63
#pragma unroll
        for (int p = 0; p < 4; ++p) {
            int k = (tid >> 4) + p * 16;
            float4 b = *(const float4*)(W + (size_t)(k0 + k) * n_out + col0 + tx * 4);
            *(float4*)&Bs[k][tx * 4] = b;
        }
        __syncthreads();
#pragma unroll 8
        for (int kk = 0; kk < 64; ++kk) {
            float4 a = *(const float4*)&As[kk][ty * 4];
            float4 b = *(const float4*)&Bs[kk][tx * 4];
            acc[0].x = fmaf(a.x, b.x, acc[0].x);
            acc[0].y = fmaf(a.x, b.y, acc[0].y);
            acc[0].z = fmaf(a.x, b.z, acc[0].z);
            acc[0].w = fmaf(a.x, b.w, acc[0].w);
            acc[1].x = fmaf(a.y, b.x, acc[1].x);
            acc[1].y = fmaf(a.y, b.y, acc[1].y);
            acc[1].z = fmaf(a.y, b.z, acc[1].z);
            acc[1].w = fmaf(a.y, b.w, acc[1].w);
            acc[2].x = fmaf(a.z, b.x, acc[2].x);
            acc[2].y = fmaf(a.z, b.y, acc[2].y);
            acc[2].z = fmaf(a.z, b.z, acc[2].z);
            acc[2].w = fmaf(a.z, b.w, acc[2].w);
            acc[3].x = fmaf(a.w, b.x, acc[3].x);
            acc[3].y = fmaf(a.w, b.y, acc[3].y);
            acc[3].z = fmaf(a.w, b.z, acc[3].z);
            acc[3].w = fmaf(a.w, b.w, acc[3].w);
        }
        __syncthreads();
    }
#pragma unroll
    for (int i = 0; i < 4; ++i) {
        int r = row0 + ty * 4 + i;
        if (r < n_rows) *(float4*)(H + (size_t)r * n_out + col0 + tx * 4) = acc[i];
    }
}

// Aggregation: out[d] = dinv[d]*( sum_{e: dst=d} dinv[s]*h[s] + dinv[d]*h[d] ) + b
// One wave per node, lane-per-dim (D=128 -> 2 regs/lane, D=64 -> 1).
template <int D, bool RELU>
__global__ __launch_bounds__(256) void agg_kernel(const float* __restrict__ H,
                                                  const int* __restrict__ csr_src,
                                                  const int* __restrict__ row_ptr,
                                                  const float* __restrict__ dinv,
                                                  const float* __restrict__ bias,
                                                  float* __restrict__ out, int n) {
    int node = blockIdx.x * 4 + threadIdx.y;
    if (node >= n) return;
    int lane = threadIdx.x;
    float acc0 = 0.f, acc1 = 0.f;
    int e = row_ptr[node];
    int end = row_ptr[node + 1];
    for (; e < end; ++e) {
        int s = csr_src[e];
        float w = dinv[s];
        const float* hs = H + (size_t)s * D;
        acc0 = fmaf(w, hs[lane], acc0);
        if (D == 128) acc1 = fmaf(w, hs[lane + 64], acc1);
    }
    float dn = dinv[node];
    const float* hn = H + (size_t)node * D;
    acc0 = fmaf(dn, hn[lane], acc0);
    acc0 = fmaf(acc0, dn, bias[lane]);
    if (RELU) acc0 = fmaxf(acc0, 0.f);
    out[(size_t)node * D + lane] = acc0;
    if (D == 128) {
        acc1 = fmaf(dn, hn[lane + 64], acc1);
        acc1 = fmaf(acc1, dn, bias[lane + 64]);
        if (RELU) acc1 = fmaxf(acc1, 0.f);
        out[(size_t)node * D + lane + 64] = acc1;
    }
}

extern "C" void kernel_launch(void* const* d_in, const int* in_sizes, int n_in,
                              void* d_out, int out_size, void* d_ws, size_t ws_size,
                              hipStream_t stream) {
    const float* x  = (const float*)d_in[0];
    const int*   ei = (const int*)d_in[1];
    const float* W1 = (const float*)d_in[2];
    const float* b1 = (const float*)d_in[3];
    const float* W2 = (const float*)d_in[4];
    const float* b2 = (const float*)d_in[5];
    const float* W3 = (const float*)d_in[6];
    const float* b3 = (const float*)d_in[7];

    const int n = in_sizes[0] / 128;   // 50000
    const int E = in_sizes[1] / 2;     // 1600000
    const int* src = ei;
    const int* dst = ei + E;

    char* ws = (char*)d_ws;
    size_t off = 0;
    auto alloc = [&](size_t bytes) {
        void* p = ws + off;
        off = (off + bytes + 511) & ~(size_t)511;
        return p;
    };
    int*   cnt     = (int*)alloc((size_t)n * 4);
    int*   row_ptr = (int*)alloc((size_t)(n + 1) * 4);
    int*   cursor  = (int*)alloc((size_t)n * 4);
    float* dinv    = (float*)alloc((size_t)n * 4);
    int*   csr_src = (int*)alloc((size_t)E * 4);
    float* bufA    = (float*)alloc((size_t)n * 128 * 4);
    float* bufB    = (float*)alloc((size_t)n * 128 * 4);
    (void)ws_size;

    hipMemsetAsync(cnt, 0, (size_t)n * 4, stream);
    hipMemsetAsync(cursor, 0, (size_t)n * 4, stream);

    count_kernel<<<(E + 255) / 256, 256, 0, stream>>>(dst, cnt, E);
    dinv_kernel<<<(n + 255) / 256, 256, 0, stream>>>(cnt, dinv, n);
    scan_kernel<<<1, 1024, 0, stream>>>(cnt, row_ptr, n);
    scatter_kernel<<<(E + 255) / 256, 256, 0, stream>>>(src, dst, row_ptr, cursor, csr_src, E);

    dim3 aggBlock(64, 4);
    int aggGrid = (n + 3) / 4;

    // layer 1: h = x@W1 ; agg + b1 + relu
    gemm_kernel<<<dim3((n + 63) / 64, 2), 256, 0, stream>>>(x, W1, bufA, n, 128);
    agg_kernel<128, true><<<aggGrid, aggBlock, 0, stream>>>(bufA, csr_src, row_ptr, dinv, b1, bufB, n);
    // layer 2
    gemm_kernel<<<dim3((n + 63) / 64, 2), 256, 0, stream>>>(bufB, W2, bufA, n, 128);
    agg_kernel<128, true><<<aggGrid, aggBlock, 0, stream>>>(bufA, csr_src, row_ptr, dinv, b2, bufB, n);
    // layer 3 (64-wide, no relu), write d_out directly
    gemm_kernel<<<dim3((n + 63) / 64, 1), 256, 0, stream>>>(bufB, W3, bufA, n, 64);
    agg_kernel<64, false><<<aggGrid, aggBlock, 0, stream>>>(bufA, csr_src, row_ptr, dinv, b3, (float*)d_out, n);
}

// Round 2
// 585.780 us; speedup vs baseline: 1.2910x; 1.2910x over previous
//
#include <hip/hip_runtime.h>

// ---------------------------------------------------------------------------
// 3-layer GCN: out = GCNConv3( relu(GCNConv2( relu(GCNConv1(x)) )) )
// GCNConv(h) = D^{-1/2} (A + I) D^{-1/2} (h W) + b, deg from dst (+self loop)
// CSR (by dst) built per call; fp32 tiled GEMM (no fp32 MFMA on CDNA4);
// gather aggregation with x8 edge unroll for MLP (latency-bound fix).
// ---------------------------------------------------------------------------

__global__ void count_kernel(const int* __restrict__ dst, int* __restrict__ cnt, int E) {
    int i = blockIdx.x * blockDim.x + threadIdx.x;
    if (i < E) atomicAdd(&cnt[dst[i]], 1);
}

__global__ void dinv_kernel(const int* __restrict__ cnt, float* __restrict__ dinv, int n) {
    int i = blockIdx.x * blockDim.x + threadIdx.x;
    if (i < n) dinv[i] = rsqrtf((float)(cnt[i] + 1));  // +1 self loop; always > 0
}

// Single-block exclusive scan of cnt[0..n) -> row_ptr[0..n]; row_ptr[n] = total.
__global__ __launch_bounds__(1024) void scan_kernel(const int* __restrict__ cnt,
                                                    int* __restrict__ row_ptr, int n) {
    __shared__ int wsum[16];
    __shared__ int chunk_total;
    const int VPT = 8;
    const int CHUNK = 1024 * VPT;
    int tid = threadIdx.x;
    int lane = tid & 63;
    int wid = tid >> 6;
    int running = 0;
    for (int base = 0; base < n; base += CHUNK) {
        int idx0 = base + tid * VPT;
        int v[VPT];
        int tsum = 0;
#pragma unroll
        for (int j = 0; j < VPT; ++j) {
            int i = idx0 + j;
            v[j] = (i < n) ? cnt[i] : 0;
            tsum += v[j];
        }
        int x = tsum;
#pragma unroll
        for (int off = 1; off < 64; off <<= 1) {
            int y = __shfl_up(x, off);
            if (lane >= off) x += y;
        }
        if (lane == 63) wsum[wid] = x;
        __syncthreads();
        if (wid == 0) {
            int ws = (lane < 16) ? wsum[lane] : 0;
#pragma unroll
            for (int off = 1; off < 16; off <<= 1) {
                int y = __shfl_up(ws, off);
                if (lane >= off) ws += y;
            }
            if (lane < 16) wsum[lane] = ws;
            if (lane == 15) chunk_total = ws;
        }
        __syncthreads();
        int woff = (wid > 0) ? wsum[wid - 1] : 0;
        int excl = running + woff + (x - tsum);
#pragma unroll
        for (int j = 0; j < VPT; ++j) {
            int i = idx0 + j;
            if (i < n) row_ptr[i] = excl;
            excl += v[j];
        }
        running += chunk_total;
        __syncthreads();
    }
    if (tid == 0) row_ptr[n] = running;
}

__global__ void scatter_kernel(const int* __restrict__ src, const int* __restrict__ dst,
                               const int* __restrict__ row_ptr, int* __restrict__ cursor,
                               int* __restrict__ csr_src, int E) {
    int i = blockIdx.x * blockDim.x + threadIdx.x;
    if (i < E) {
        int d = dst[i];
        int pos = row_ptr[d] + atomicAdd(&cursor[d], 1);
        csr_src[pos] = src[i];
    }
}

// fp32 GEMM: H[n_rows][n_out] = X[n_rows][128] * W[128][n_out].
// BM=BN=BK=64, 256 threads, 4x4 microtile, A transposed in LDS (float4 frags).
__global__ __launch_bounds__(256) void gemm_kernel(const float* __restrict__ X,
                                                   const float* __restrict__ W,
                                                   float* __restrict__ H,
                                                   int n_rows, int n_out) {
    __shared__ float As[64][68];
    __shared__ float Bs[64][68];
    int tid = threadIdx.x;
    int tx = tid & 15;
    int ty = tid >> 4;
    int row0 = blockIdx.x * 64;
    int col0 = blockIdx.y * 64;
    float4 acc[4];
#pragma unroll
    for (int i = 0; i < 4; ++i) acc[i] = make_float4(0.f, 0.f, 0.f, 0.f);

    for (int k0 = 0; k0 < 128; k0 += 64) {
#pragma unroll
        for (int p = 0; p < 4; ++p) {
            int r = (tid >> 4) + p * 16;
            int grow = row0 + r;
            int kk = tx * 4;
            float4 a = make_float4(0.f, 0.f, 0.f, 0.f);
            if (grow < n_rows) a = *(const float4*)(X + (size_t)grow * 128 + k0 + kk);
            As[kk + 0][r] = a.x;
            As[kk + 1][r] = a.y;
            As[kk + 2][r] = a.z;
            As[kk + 3][r] = a.w;
        }
#pragma unroll
        for (int p = 0; p < 4; ++p) {
            int k = (tid >> 4) + p * 16;
            float4 b = *(const float4*)(W + (size_t)(k0 + k) * n_out + col0 + tx * 4);
            *(float4*)&Bs[k][tx * 4] = b;
        }
        __syncthreads();
#pragma unroll 8
        for (int kk = 0; kk < 64; ++kk) {
            float4 a = *(const float4*)&As[kk][ty * 4];
            float4 b = *(const float4*)&Bs[kk][tx * 4];
            acc[0].x = fmaf(a.x, b.x, acc[0].x);
            acc[0].y = fmaf(a.x, b.y, acc[0].y);
            acc[0].z = fmaf(a.x, b.z, acc[0].z);
            acc[0].w = fmaf(a.x, b.w, acc[0].w);
            acc[1].x = fmaf(a.y, b.x, acc[1].x);
            acc[1].y = fmaf(a.y, b.y, acc[1].y);
            acc[1].z = fmaf(a.y, b.z, acc[1].z);
            acc[1].w = fmaf(a.y, b.w, acc[1].w);
            acc[2].x = fmaf(a.z, b.x, acc[2].x);
            acc[2].y = fmaf(a.z, b.y, acc[2].y);
            acc[2].z = fmaf(a.z, b.z, acc[2].z);
            acc[2].w = fmaf(a.z, b.w, acc[2].w);
            acc[3].x = fmaf(a.w, b.x, acc[3].x);
            acc[3].y = fmaf(a.w, b.y, acc[3].y);
            acc[3].z = fmaf(a.w, b.z, acc[3].z);
            acc[3].w = fmaf(a.w, b.w, acc[3].w);
        }
        __syncthreads();
    }
#pragma unroll
    for (int i = 0; i < 4; ++i) {
        int r = row0 + ty * 4 + i;
        if (r < n_rows) *(float4*)(H + (size_t)r * n_out + col0 + tx * 4) = acc[i];
    }
}

// Aggregation D=128: out[d] = dinv[d]*( sum_e dinv[s]*h[s] + dinv[d]*h[d] ) + b
// One wave per node, float2 per lane (whole 512B row in one dwordx2 per wave),
// edge loop unrolled x8 so 8 gather chains are in flight (MLP for latency).
template <bool RELU>
__global__ __launch_bounds__(256) void agg128_kernel(const float* __restrict__ H,
                                                     const int* __restrict__ csr_src,
                                                     const int* __restrict__ row_ptr,
                                                     const float* __restrict__ dinv,
                                                     const float* __restrict__ bias,
                                                     float* __restrict__ out, int n) {
    int node = blockIdx.x * 4 + threadIdx.y;
    if (node >= n) return;
    int lane = threadIdx.x;
    float2 acc = make_float2(0.f, 0.f);
    int e = row_ptr[node];
    int end = row_ptr[node + 1];
    for (; e + 8 <= end; e += 8) {
        int s[8];
#pragma unroll
        for (int j = 0; j < 8; ++j) s[j] = csr_src[e + j];
        float w[8];
        float2 a[8];
#pragma unroll
        for (int j = 0; j < 8; ++j) {
            w[j] = dinv[s[j]];
            a[j] = *(const float2*)(H + (size_t)s[j] * 128 + lane * 2);
        }
#pragma unroll
        for (int j = 0; j < 8; ++j) {
            acc.x = fmaf(w[j], a[j].x, acc.x);
            acc.y = fmaf(w[j], a[j].y, acc.y);
        }
    }
    for (; e < end; ++e) {
        int s = csr_src[e];
        float w = dinv[s];
        float2 a = *(const float2*)(H + (size_t)s * 128 + lane * 2);
        acc.x = fmaf(w, a.x, acc.x);
        acc.y = fmaf(w, a.y, acc.y);
    }
    float dn = dinv[node];
    float2 hn = *(const float2*)(H + (size_t)node * 128 + lane * 2);
    float2 bb = *(const float2*)(bias + lane * 2);
    acc.x = fmaf(dn, hn.x, acc.x);
    acc.y = fmaf(dn, hn.y, acc.y);
    acc.x = fmaf(acc.x, dn, bb.x);
    acc.y = fmaf(acc.y, dn, bb.y);
    if (RELU) {
        acc.x = fmaxf(acc.x, 0.f);
        acc.y = fmaxf(acc.y, 0.f);
    }
    *(float2*)(out + (size_t)node * 128 + lane * 2) = acc;
}

// Aggregation D=64 (final layer, no relu): lane-per-dim, x8 unroll.
__global__ __launch_bounds__(256) void agg64_kernel(const float* __restrict__ H,
                                                    const int* __restrict__ csr_src,
                                                    const int* __restrict__ row_ptr,
                                                    const float* __restrict__ dinv,
                                                    const float* __restrict__ bias,
                                                    float* __restrict__ out, int n) {
    int node = blockIdx.x * 4 + threadIdx.y;
    if (node >= n) return;
    int lane = threadIdx.x;
    float acc = 0.f;
    int e = row_ptr[node];
    int end = row_ptr[node + 1];
    for (; e + 8 <= end; e += 8) {
        int s[8];
#pragma unroll
        for (int j = 0; j < 8; ++j) s[j] = csr_src[e + j];
        float w[8];
        float a[8];
#pragma unroll
        for (int j = 0; j < 8; ++j) {
            w[j] = dinv[s[j]];
            a[j] = H[(size_t)s[j] * 64 + lane];
        }
#pragma unroll
        for (int j = 0; j < 8; ++j) acc = fmaf(w[j], a[j], acc);
    }
    for (; e < end; ++e) {
        int s = csr_src[e];
        acc = fmaf(dinv[s], H[(size_t)s * 64 + lane], acc);
    }
    float dn = dinv[node];
    acc = fmaf(dn, H[(size_t)node * 64 + lane], acc);
    acc = fmaf(acc, dn, bias[lane]);
    out[(size_t)node * 64 + lane] = acc;
}

extern "C" void kernel_launch(void* const* d_in, const int* in_sizes, int n_in,
                              void* d_out, int out_size, void* d_ws, size_t ws_size,
                              hipStream_t stream) {
    const float* x  = (const float*)d_in[0];
    const int*   ei = (const int*)d_in[1];
    const float* W1 = (const float*)d_in[2];
    const float* b1 = (const float*)d_in[3];
    const float* W2 = (const float*)d_in[4];
    const float* b2 = (const float*)d_in[5];
    const float* W3 = (const float*)d_in[6];
    const float* b3 = (const float*)d_in[7];

    const int n = in_sizes[0] / 128;   // 50000
    const int E = in_sizes[1] / 2;     // 1600000
    const int* src = ei;
    const int* dst = ei + E;

    char* ws = (char*)d_ws;
    size_t off = 0;
    auto alloc = [&](size_t bytes) {
        void* p = ws + off;
        off = (off + bytes + 511) & ~(size_t)511;
        return p;
    };
    int*   cnt     = (int*)alloc((size_t)n * 4);
    int*   row_ptr = (int*)alloc((size_t)(n + 1) * 4);
    int*   cursor  = (int*)alloc((size_t)n * 4);
    float* dinv    = (float*)alloc((size_t)n * 4);
    int*   csr_src = (int*)alloc((size_t)E * 4);
    float* bufA    = (float*)alloc((size_t)n * 128 * 4);
    float* bufB    = (float*)alloc((size_t)n * 128 * 4);
    (void)ws_size;

    hipMemsetAsync(cnt, 0, (size_t)n * 4, stream);
    hipMemsetAsync(cursor, 0, (size_t)n * 4, stream);

    count_kernel<<<(E + 255) / 256, 256, 0, stream>>>(dst, cnt, E);
    dinv_kernel<<<(n + 255) / 256, 256, 0, stream>>>(cnt, dinv, n);
    scan_kernel<<<1, 1024, 0, stream>>>(cnt, row_ptr, n);
    scatter_kernel<<<(E + 255) / 256, 256, 0, stream>>>(src, dst, row_ptr, cursor, csr_src, E);

    dim3 aggBlock(64, 4);
    int aggGrid = (n + 3) / 4;

    // layer 1
    gemm_kernel<<<dim3((n + 63) / 64, 2), 256, 0, stream>>>(x, W1, bufA, n, 128);
    agg128_kernel<true><<<aggGrid, aggBlock, 0, stream>>>(bufA, csr_src, row_ptr, dinv, b1, bufB, n);
    // layer 2
    gemm_kernel<<<dim3((n + 63) / 64, 2), 256, 0, stream>>>(bufB, W2, bufA, n, 128);
    agg128_kernel<true><<<aggGrid, aggBlock, 0, stream>>>(bufA, csr_src, row_ptr, dinv, b2, bufB, n);
    // layer 3 (64-wide, no relu)
    gemm_kernel<<<dim3((n + 63) / 64, 1), 256, 0, stream>>>(bufB, W3, bufA, n, 64);
    agg64_kernel<<<aggGrid, aggBlock, 0, stream>>>(bufA, csr_src, row_ptr, dinv, b3, (float*)d_out, n);
}

// Round 4
// 413.754 us; speedup vs baseline: 1.8278x; 1.4158x over previous
//
#include <hip/hip_runtime.h>

// ---------------------------------------------------------------------------
// 3-layer GCN: out = GCNConv3( relu(GCNConv2( relu(GCNConv1(x)) )) )
// GCNConv(h) = D^{-1/2} (A + I) D^{-1/2} (h W) + b, deg = in-degree + 1.
// CSR build is bucketed (dst>>8): block-local LDS bucket sort -> coalesced
// pair dump + directory; then one block per bucket builds row_ptr/dinv/csr_src
// with LDS-only atomics and L2-resident dense writes.
// NOTE: pair_buf must hold NB*EPB entries (padded last block!), dir after it.
// fp32 tiled GEMM (no fp32 MFMA on CDNA4); gather aggregation, x8 edge unroll.
// ---------------------------------------------------------------------------

#define EPB  4096   // edges per bin block
#define DIRW 197    // directory row width = max buckets (50176/256) + 1

// --- CSR build stage 1: per-block bucket sort of (src,dst), dump + directory.
__global__ __launch_bounds__(256) void bin_kernel(const int* __restrict__ src,
                                                  const int* __restrict__ dst,
                                                  int2* __restrict__ pair_buf,
                                                  int* __restrict__ dir,
                                                  int* __restrict__ bucket_cnt,
                                                  int E, int nbkt) {
    __shared__ int2 stage[EPB];      // 32 KB
    __shared__ int hist[DIRW];
    __shared__ int sc[256];
    __shared__ int cur[DIRW];
    int tid = threadIdx.x;
    int blk = blockIdx.x;
    if (tid < DIRW) hist[tid] = 0;
    __syncthreads();

    int s_reg[16], d_reg[16];
#pragma unroll
    for (int j = 0; j < 16; ++j) {
        int gi = blk * EPB + j * 256 + tid;
        int s = 0, d = nbkt << 8;          // invalid -> trash bucket nbkt
        if (gi < E) { s = src[gi]; d = dst[gi]; }
        s_reg[j] = s; d_reg[j] = d;
        atomicAdd(&hist[d >> 8], 1);
    }
    __syncthreads();
    // exclusive scan of hist[0..nbkt] (<=197 entries) via Hillis-Steele
    int h = (tid < DIRW) ? hist[tid] : 0;
    sc[tid] = h;
    __syncthreads();
#pragma unroll
    for (int off = 1; off < 256; off <<= 1) {
        int v = (tid >= off) ? sc[tid - off] : 0;
        __syncthreads();
        sc[tid] += v;
        __syncthreads();
    }
    if (tid < DIRW) {
        int st = sc[tid] - h;
        cur[tid] = st;
        dir[blk * DIRW + tid] = st;
        if (tid < nbkt && h > 0) atomicAdd(&bucket_cnt[tid], h);
    }
    __syncthreads();
#pragma unroll
    for (int j = 0; j < 16; ++j) {
        int b = d_reg[j] >> 8;
        int slot = atomicAdd(&cur[b], 1);
        stage[slot] = make_int2(s_reg[j], d_reg[j]);
    }
    __syncthreads();
#pragma unroll
    for (int j = 0; j < 16; ++j) {
        int idx = j * 256 + tid;
        pair_buf[blk * EPB + idx] = stage[idx];   // coalesced 8B dump
    }
}

// --- CSR build stage 2: exclusive scan of bucket counts -> bucket bases.
__global__ __launch_bounds__(256) void bucket_scan_kernel(const int* __restrict__ bucket_cnt,
                                                          int* __restrict__ bucket_base,
                                                          int nbkt) {
    __shared__ int sc[256];
    int tid = threadIdx.x;
    int h = (tid < nbkt) ? bucket_cnt[tid] : 0;
    sc[tid] = h;
    __syncthreads();
#pragma unroll
    for (int off = 1; off < 256; off <<= 1) {
        int v = (tid >= off) ? sc[tid - off] : 0;
        __syncthreads();
        sc[tid] += v;
        __syncthreads();
    }
    if (tid <= nbkt) bucket_base[tid] = sc[tid] - h;   // tid==nbkt: h=0 -> total
}

// --- CSR build stage 3: one block per bucket (256 dsts). Count -> scan ->
// row_ptr/dinv; then place csr_src with LDS cursors (L2-resident writes).
__global__ __launch_bounds__(512) void csr_kernel(const int2* __restrict__ pair_buf,
                                                  const int* __restrict__ dir,
                                                  const int* __restrict__ bucket_base,
                                                  int* __restrict__ row_ptr,
                                                  float* __restrict__ dinv,
                                                  int* __restrict__ csr_src,
                                                  int n, int NB, int nbkt) {
    __shared__ int dstart[400];
    __shared__ int dend[400];
    __shared__ int cnt[256];
    __shared__ int sc[256];
    __shared__ int cur[256];
    int tid = threadIdx.x;
    int b = blockIdx.x;
    for (int i = tid; i < NB; i += 512) {
        dstart[i] = dir[i * DIRW + b];
        dend[i]   = dir[i * DIRW + b + 1];
    }
    if (tid < 256) cnt[tid] = 0;
    __syncthreads();
    int wid = tid >> 6, lane = tid & 63;
    for (int seg = wid; seg < NB; seg += 8) {
        int s0 = dstart[seg], s1 = dend[seg];
        for (int k = s0 + lane; k < s1; k += 64) {
            int2 p = pair_buf[(size_t)seg * EPB + k];
            atomicAdd(&cnt[p.y & 255], 1);
        }
    }
    __syncthreads();
    int c = (tid < 256) ? cnt[tid] : 0;
    if (tid < 256) sc[tid] = c;
    __syncthreads();
#pragma unroll
    for (int off = 1; off < 256; off <<= 1) {
        int v = 0;
        if (tid < 256 && tid >= off) v = sc[tid - off];
        __syncthreads();
        if (tid < 256) sc[tid] += v;
        __syncthreads();
    }
    int base = bucket_base[b];
    if (tid < 256) {
        int excl = sc[tid] - c;
        cur[tid] = excl;
        int d = b * 256 + tid;
        if (d < n) {
            row_ptr[d] = base + excl;
            dinv[d] = rsqrtf((float)(c + 1));   // +1 self loop
        }
    }
    if (b == 0 && tid == 0) row_ptr[n] = bucket_base[nbkt];
    __syncthreads();
    for (int seg = wid; seg < NB; seg += 8) {
        int s0 = dstart[seg], s1 = dend[seg];
        for (int k = s0 + lane; k < s1; k += 64) {
            int2 p = pair_buf[(size_t)seg * EPB + k];
            int pos = atomicAdd(&cur[p.y & 255], 1);
            csr_src[base + pos] = p.x;
        }
    }
}

// fp32 GEMM: H[n_rows][n_out] = X[n_rows][128] * W[128][n_out].
// BM=BN=BK=64, 256 threads, 4x4 microtile, A transposed in LDS (float4 frags).
__global__ __launch_bounds__(256) void gemm_kernel(const float* __restrict__ X,
                                                   const float* __restrict__ W,
                                                   float* __restrict__ H,
                                                   int n_rows, int n_out) {
    __shared__ float As[64][68];
    __shared__ float Bs[64][68];
    int tid = threadIdx.x;
    int tx = tid & 15;
    int ty = tid >> 4;
    int row0 = blockIdx.x * 64;
    int col0 = blockIdx.y * 64;
    float4 acc[4];
#pragma unroll
    for (int i = 0; i < 4; ++i) acc[i] = make_float4(0.f, 0.f, 0.f, 0.f);

    for (int k0 = 0; k0 < 128; k0 += 64) {
#pragma unroll
        for (int p = 0; p < 4; ++p) {
            int r = (tid >> 4) + p * 16;
            int grow = row0 + r;
            int kk = tx * 4;
            float4 a = make_float4(0.f, 0.f, 0.f, 0.f);
            if (grow < n_rows) a = *(const float4*)(X + (size_t)grow * 128 + k0 + kk);
            As[kk + 0][r] = a.x;
            As[kk + 1][r] = a.y;
            As[kk + 2][r] = a.z;
            As[kk + 3][r] = a.w;
        }
#pragma unroll
        for (int p = 0; p < 4; ++p) {
            int k = (tid >> 4) + p * 16;
            float4 b = *(const float4*)(W + (size_t)(k0 + k) * n_out + col0 + tx * 4);
            *(float4*)&Bs[k][tx * 4] = b;
        }
        __syncthreads();
#pragma unroll 8
        for (int kk = 0; kk < 64; ++kk) {
            float4 a = *(const float4*)&As[kk][ty * 4];
            float4 b = *(const float4*)&Bs[kk][tx * 4];
            acc[0].x = fmaf(a.x, b.x, acc[0].x);
            acc[0].y = fmaf(a.x, b.y, acc[0].y);
            acc[0].z = fmaf(a.x, b.z, acc[0].z);
            acc[0].w = fmaf(a.x, b.w, acc[0].w);
            acc[1].x = fmaf(a.y, b.x, acc[1].x);
            acc[1].y = fmaf(a.y, b.y, acc[1].y);
            acc[1].z = fmaf(a.y, b.z, acc[1].z);
            acc[1].w = fmaf(a.y, b.w, acc[1].w);
            acc[2].x = fmaf(a.z, b.x, acc[2].x);
            acc[2].y = fmaf(a.z, b.y, acc[2].y);
            acc[2].z = fmaf(a.z, b.z, acc[2].z);
            acc[2].w = fmaf(a.z, b.w, acc[2].w);
            acc[3].x = fmaf(a.w, b.x, acc[3].x);
            acc[3].y = fmaf(a.w, b.y, acc[3].y);
            acc[3].z = fmaf(a.w, b.z, acc[3].z);
            acc[3].w = fmaf(a.w, b.w, acc[3].w);
        }
        __syncthreads();
    }
#pragma unroll
    for (int i = 0; i < 4; ++i) {
        int r = row0 + ty * 4 + i;
        if (r < n_rows) *(float4*)(H + (size_t)r * n_out + col0 + tx * 4) = acc[i];
    }
}

// Aggregation D=128: out[d] = dinv[d]*( sum_e dinv[s]*h[s] + dinv[d]*h[d] ) + b
// One wave per node, float2 per lane, edge loop unrolled x8 (8 gathers in flight).
template <bool RELU>
__global__ __launch_bounds__(256) void agg128_kernel(const float* __restrict__ H,
                                                     const int* __restrict__ csr_src,
                                                     const int* __restrict__ row_ptr,
                                                     const float* __restrict__ dinv,
                                                     const float* __restrict__ bias,
                                                     float* __restrict__ out, int n) {
    int node = blockIdx.x * 4 + threadIdx.y;
    if (node >= n) return;
    int lane = threadIdx.x;
    float2 acc = make_float2(0.f, 0.f);
    int e = row_ptr[node];
    int end = row_ptr[node + 1];
    for (; e + 8 <= end; e += 8) {
        int s[8];
#pragma unroll
        for (int j = 0; j < 8; ++j) s[j] = csr_src[e + j];
        float w[8];
        float2 a[8];
#pragma unroll
        for (int j = 0; j < 8; ++j) {
            w[j] = dinv[s[j]];
            a[j] = *(const float2*)(H + (size_t)s[j] * 128 + lane * 2);
        }
#pragma unroll
        for (int j = 0; j < 8; ++j) {
            acc.x = fmaf(w[j], a[j].x, acc.x);
            acc.y = fmaf(w[j], a[j].y, acc.y);
        }
    }
    for (; e < end; ++e) {
        int s = csr_src[e];
        float w = dinv[s];
        float2 a = *(const float2*)(H + (size_t)s * 128 + lane * 2);
        acc.x = fmaf(w, a.x, acc.x);
        acc.y = fmaf(w, a.y, acc.y);
    }
    float dn = dinv[node];
    float2 hn = *(const float2*)(H + (size_t)node * 128 + lane * 2);
    float2 bb = *(const float2*)(bias + lane * 2);
    acc.x = fmaf(dn, hn.x, acc.x);
    acc.y = fmaf(dn, hn.y, acc.y);
    acc.x = fmaf(acc.x, dn, bb.x);
    acc.y = fmaf(acc.y, dn, bb.y);
    if (RELU) {
        acc.x = fmaxf(acc.x, 0.f);
        acc.y = fmaxf(acc.y, 0.f);
    }
    *(float2*)(out + (size_t)node * 128 + lane * 2) = acc;
}

// Aggregation D=64 (final layer, no relu): lane-per-dim, x8 unroll.
__global__ __launch_bounds__(256) void agg64_kernel(const float* __restrict__ H,
                                                    const int* __restrict__ csr_src,
                                                    const int* __restrict__ row_ptr,
                                                    const float* __restrict__ dinv,
                                                    const float* __restrict__ bias,
                                                    float* __restrict__ out, int n) {
    int node = blockIdx.x * 4 + threadIdx.y;
    if (node >= n) return;
    int lane = threadIdx.x;
    float acc = 0.f;
    int e = row_ptr[node];
    int end = row_ptr[node + 1];
    for (; e + 8 <= end; e += 8) {
        int s[8];
#pragma unroll
        for (int j = 0; j < 8; ++j) s[j] = csr_src[e + j];
        float w[8];
        float a[8];
#pragma unroll
        for (int j = 0; j < 8; ++j) {
            w[j] = dinv[s[j]];
            a[j] = H[(size_t)s[j] * 64 + lane];
        }
#pragma unroll
        for (int j = 0; j < 8; ++j) acc = fmaf(w[j], a[j], acc);
    }
    for (; e < end; ++e) {
        int s = csr_src[e];
        acc = fmaf(dinv[s], H[(size_t)s * 64 + lane], acc);
    }
    float dn = dinv[node];
    acc = fmaf(dn, H[(size_t)node * 64 + lane], acc);
    acc = fmaf(acc, dn, bias[lane]);
    out[(size_t)node * 64 + lane] = acc;
}

extern "C" void kernel_launch(void* const* d_in, const int* in_sizes, int n_in,
                              void* d_out, int out_size, void* d_ws, size_t ws_size,
                              hipStream_t stream) {
    const float* x  = (const float*)d_in[0];
    const int*   ei = (const int*)d_in[1];
    const float* W1 = (const float*)d_in[2];
    const float* b1 = (const float*)d_in[3];
    const float* W2 = (const float*)d_in[4];
    const float* b2 = (const float*)d_in[5];
    const float* W3 = (const float*)d_in[6];
    const float* b3 = (const float*)d_in[7];

    const int n = in_sizes[0] / 128;   // 50000
    const int E = in_sizes[1] / 2;     // 1600000
    const int* src = ei;
    const int* dst = ei + E;
    const int nbkt = (n + 255) >> 8;           // 196
    const int NB = (E + EPB - 1) / EPB;        // 391

    char* ws = (char*)d_ws;
    size_t off = 0;
    auto alloc = [&](size_t bytes) {
        void* p = ws + off;
        off = (off + bytes + 511) & ~(size_t)511;
        return p;
    };
    int*   bucket_cnt  = (int*)alloc(256 * 4);
    int*   bucket_base = (int*)alloc(256 * 4);
    int*   row_ptr     = (int*)alloc((size_t)(n + 1) * 4);
    float* dinv        = (float*)alloc((size_t)n * 4);
    int*   csr_src     = (int*)alloc((size_t)E * 4);
    float* bufA        = (float*)alloc((size_t)n * 128 * 4);
    float* bufB        = (float*)alloc((size_t)n * 128 * 4);
    // pair_buf + dir alias bufA: only live before the first GEMM writes bufA.
    // pair_buf is NB*EPB entries (bin_kernel dumps padded blocks!), dir after.
    int2* pair_buf = (int2*)bufA;                                       // 12.81 MB
    int*  dir      = (int*)((char*)bufA + (size_t)NB * EPB * 8);        // 308 KB
    // total aliased: ~13.1 MB < 25.6 MB bufA. OK.
    (void)ws_size;

    hipMemsetAsync(bucket_cnt, 0, 256 * 4, stream);

    bin_kernel<<<NB, 256, 0, stream>>>(src, dst, pair_buf, dir, bucket_cnt, E, nbkt);
    bucket_scan_kernel<<<1, 256, 0, stream>>>(bucket_cnt, bucket_base, nbkt);
    csr_kernel<<<nbkt, 512, 0, stream>>>(pair_buf, dir, bucket_base, row_ptr, dinv,
                                         csr_src, n, NB, nbkt);

    dim3 aggBlock(64, 4);
    int aggGrid = (n + 3) / 4;

    // layer 1
    gemm_kernel<<<dim3((n + 63) / 64, 2), 256, 0, stream>>>(x, W1, bufA, n, 128);
    agg128_kernel<true><<<aggGrid, aggBlock, 0, stream>>>(bufA, csr_src, row_ptr, dinv, b1, bufB, n);
    // layer 2
    gemm_kernel<<<dim3((n + 63) / 64, 2), 256, 0, stream>>>(bufB, W2, bufA, n, 128);
    agg128_kernel<true><<<aggGrid, aggBlock, 0, stream>>>(bufA, csr_src, row_ptr, dinv, b2, bufB, n);
    // layer 3 (64-wide, no relu)
    gemm_kernel<<<dim3((n + 63) / 64, 1), 256, 0, stream>>>(bufB, W3, bufA, n, 64);
    agg64_kernel<<<aggGrid, aggBlock, 0, stream>>>(bufA, csr_src, row_ptr, dinv, b3, (float*)d_out, n);
}

// Round 5
// 294.950 us; speedup vs baseline: 2.5640x; 1.4028x over previous
//
#include <hip/hip_runtime.h>

// ---------------------------------------------------------------------------
// 3-layer GCN, bf16 H-pipeline:
//   GEMM (MFMA bf16, fp32 accum) -> H stored bf16 (halves gather bytes)
//   agg gathers bf16 rows, fp32 accumulate + bias (+relu), writes fp32
// CSR build: bucketed sort (unchanged from round 4).
// Accuracy: quantization errors incoherent across aggregated sources ->
// attenuated ~0.17x per agg; predicted final absmax ~3e-4 < 6.5e-4 thr.
// ---------------------------------------------------------------------------

#define EPB  4096   // edges per bin block
#define DIRW 197    // directory row width = max buckets (50176/256) + 1

typedef __attribute__((ext_vector_type(8))) short bf16x8;
typedef __attribute__((ext_vector_type(4))) float f32x4;

__device__ __forceinline__ unsigned short f2bf(float f) {
    unsigned int u = __float_as_uint(f);
    u += 0x7FFFu + ((u >> 16) & 1u);   // round-to-nearest-even
    return (unsigned short)(u >> 16);
}

// --- CSR build stage 1: per-block bucket sort of (src,dst), dump + directory.
__global__ __launch_bounds__(256) void bin_kernel(const int* __restrict__ src,
                                                  const int* __restrict__ dst,
                                                  int2* __restrict__ pair_buf,
                                                  int* __restrict__ dir,
                                                  int* __restrict__ bucket_cnt,
                                                  int E, int nbkt) {
    __shared__ int2 stage[EPB];      // 32 KB
    __shared__ int hist[DIRW];
    __shared__ int sc[256];
    __shared__ int cur[DIRW];
    int tid = threadIdx.x;
    int blk = blockIdx.x;
    if (tid < DIRW) hist[tid] = 0;
    __syncthreads();

    int s_reg[16], d_reg[16];
#pragma unroll
    for (int j = 0; j < 16; ++j) {
        int gi = blk * EPB + j * 256 + tid;
        int s = 0, d = nbkt << 8;          // invalid -> trash bucket nbkt
        if (gi < E) { s = src[gi]; d = dst[gi]; }
        s_reg[j] = s; d_reg[j] = d;
        atomicAdd(&hist[d >> 8], 1);
    }
    __syncthreads();
    int h = (tid < DIRW) ? hist[tid] : 0;
    sc[tid] = h;
    __syncthreads();
#pragma unroll
    for (int off = 1; off < 256; off <<= 1) {
        int v = (tid >= off) ? sc[tid - off] : 0;
        __syncthreads();
        sc[tid] += v;
        __syncthreads();
    }
    if (tid < DIRW) {
        int st = sc[tid] - h;
        cur[tid] = st;
        dir[blk * DIRW + tid] = st;
        if (tid < nbkt && h > 0) atomicAdd(&bucket_cnt[tid], h);
    }
    __syncthreads();
#pragma unroll
    for (int j = 0; j < 16; ++j) {
        int b = d_reg[j] >> 8;
        int slot = atomicAdd(&cur[b], 1);
        stage[slot] = make_int2(s_reg[j], d_reg[j]);
    }
    __syncthreads();
#pragma unroll
    for (int j = 0; j < 16; ++j) {
        int idx = j * 256 + tid;
        pair_buf[blk * EPB + idx] = stage[idx];   // coalesced 8B dump
    }
}

// --- CSR build stage 2: exclusive scan of bucket counts -> bucket bases.
__global__ __launch_bounds__(256) void bucket_scan_kernel(const int* __restrict__ bucket_cnt,
                                                          int* __restrict__ bucket_base,
                                                          int nbkt) {
    __shared__ int sc[256];
    int tid = threadIdx.x;
    int h = (tid < nbkt) ? bucket_cnt[tid] : 0;
    sc[tid] = h;
    __syncthreads();
#pragma unroll
    for (int off = 1; off < 256; off <<= 1) {
        int v = (tid >= off) ? sc[tid - off] : 0;
        __syncthreads();
        sc[tid] += v;
        __syncthreads();
    }
    if (tid <= nbkt) bucket_base[tid] = sc[tid] - h;
}

// --- CSR build stage 3: one block per bucket (256 dsts).
__global__ __launch_bounds__(512) void csr_kernel(const int2* __restrict__ pair_buf,
                                                  const int* __restrict__ dir,
                                                  const int* __restrict__ bucket_base,
                                                  int* __restrict__ row_ptr,
                                                  float* __restrict__ dinv,
                                                  int* __restrict__ csr_src,
                                                  int n, int NB, int nbkt) {
    __shared__ int dstart[400];
    __shared__ int dend[400];
    __shared__ int cnt[256];
    __shared__ int sc[256];
    __shared__ int cur[256];
    int tid = threadIdx.x;
    int b = blockIdx.x;
    for (int i = tid; i < NB; i += 512) {
        dstart[i] = dir[i * DIRW + b];
        dend[i]   = dir[i * DIRW + b + 1];
    }
    if (tid < 256) cnt[tid] = 0;
    __syncthreads();
    int wid = tid >> 6, lane = tid & 63;
    for (int seg = wid; seg < NB; seg += 8) {
        int s0 = dstart[seg], s1 = dend[seg];
        for (int k = s0 + lane; k < s1; k += 64) {
            int2 p = pair_buf[(size_t)seg * EPB + k];
            atomicAdd(&cnt[p.y & 255], 1);
        }
    }
    __syncthreads();
    int c = (tid < 256) ? cnt[tid] : 0;
    if (tid < 256) sc[tid] = c;
    __syncthreads();
#pragma unroll
    for (int off = 1; off < 256; off <<= 1) {
        int v = 0;
        if (tid < 256 && tid >= off) v = sc[tid - off];
        __syncthreads();
        if (tid < 256) sc[tid] += v;
        __syncthreads();
    }
    int base = bucket_base[b];
    if (tid < 256) {
        int excl = sc[tid] - c;
        cur[tid] = excl;
        int d = b * 256 + tid;
        if (d < n) {
            row_ptr[d] = base + excl;
            dinv[d] = rsqrtf((float)(c + 1));   // +1 self loop
        }
    }
    if (b == 0 && tid == 0) row_ptr[n] = bucket_base[nbkt];
    __syncthreads();
    for (int seg = wid; seg < NB; seg += 8) {
        int s0 = dstart[seg], s1 = dend[seg];
        for (int k = s0 + lane; k < s1; k += 64) {
            int2 p = pair_buf[(size_t)seg * EPB + k];
            int pos = atomicAdd(&cur[p.y & 255], 1);
            csr_src[base + pos] = p.x;
        }
    }
}

// --- MFMA bf16 GEMM: H_bf16[n_rows][NOUT] = X_f32[n_rows][128] * W_f32[128][NOUT]
// Block: 256 thr = 4 waves, BM=64 rows, full N width, full K=128 in LDS.
// Operand layout (gfx950 16x16x32): lane l -> row/col (l&15),
// k = (l>>4)*4 + j in two 16-k halves. C/D: col=lane&15, row=(lane>>4)*4+reg.
template <int NOUT>
__global__ __launch_bounds__(256) void gemm_bf16_kernel(const float* __restrict__ X,
                                                        const float* __restrict__ W,
                                                        unsigned short* __restrict__ H,
                                                        int n_rows) {
    __shared__ short As[64][132];     // [m][k], pad->stride 264B (8B-aligned, conflict-free)
    __shared__ short Bs[NOUT][132];   // [n][k] (W transposed at stage time)
    int tid = threadIdx.x;
    int row0 = blockIdx.x * 64;

    // stage A: 64 rows x 128 k; 4 threads/row, 32 cols each, f32->bf16
    {
        int r = tid >> 2;
        int c0 = (tid & 3) * 32;
        int grow = row0 + r;
        const float* xp = X + (size_t)grow * 128 + c0;
#pragma unroll
        for (int j = 0; j < 8; ++j) {
            float4 v = (grow < n_rows) ? *(const float4*)(xp + j * 4)
                                       : make_float4(0.f, 0.f, 0.f, 0.f);
            ushort4 p = { f2bf(v.x), f2bf(v.y), f2bf(v.z), f2bf(v.w) };
            *(ushort4*)&As[r][c0 + j * 4] = p;
        }
    }
    // stage B: W[128][NOUT] f32 -> Bs[n][k] bf16 (transposed scatter)
    {
        int k = tid >> 1;
        int nb = (tid & 1) * (NOUT / 2);
        const float* wp = W + (size_t)k * NOUT + nb;
#pragma unroll
        for (int j = 0; j < NOUT / 8; ++j) {
            float4 v = *(const float4*)(wp + j * 4);
            int nn = nb + j * 4;
            Bs[nn + 0][k] = (short)f2bf(v.x);
            Bs[nn + 1][k] = (short)f2bf(v.y);
            Bs[nn + 2][k] = (short)f2bf(v.z);
            Bs[nn + 3][k] = (short)f2bf(v.w);
        }
    }
    __syncthreads();

    int w = tid >> 6, l = tid & 63, lr = l & 15, lg = l >> 4;
    constexpr int NF = NOUT / 16;
    f32x4 acc[NF];
#pragma unroll
    for (int i = 0; i < NF; ++i) acc[i] = (f32x4){0.f, 0.f, 0.f, 0.f};
    int arow = w * 16 + lr;

#pragma unroll
    for (int kc = 0; kc < 128; kc += 32) {
        bf16x8 a;
        ((long long*)&a)[0] = *(const long long*)&As[arow][kc + lg * 4];
        ((long long*)&a)[1] = *(const long long*)&As[arow][kc + 16 + lg * 4];
#pragma unroll
        for (int nf = 0; nf < NF; ++nf) {
            bf16x8 b;
            ((long long*)&b)[0] = *(const long long*)&Bs[nf * 16 + lr][kc + lg * 4];
            ((long long*)&b)[1] = *(const long long*)&Bs[nf * 16 + lr][kc + 16 + lg * 4];
            acc[nf] = __builtin_amdgcn_mfma_f32_16x16x32_bf16(a, b, acc[nf], 0, 0, 0);
        }
    }
    int grow_base = row0 + w * 16 + lg * 4;
#pragma unroll
    for (int nf = 0; nf < NF; ++nf) {
#pragma unroll
        for (int r = 0; r < 4; ++r) {
            int gr = grow_base + r;
            if (gr < n_rows) H[(size_t)gr * NOUT + nf * 16 + lr] = f2bf(acc[nf][r]);
        }
    }
}

// --- Aggregation D=128 (bf16 gather payload, fp32 accum/out), x8 edge unroll.
template <bool RELU>
__global__ __launch_bounds__(256) void agg128_kernel(const unsigned short* __restrict__ H,
                                                     const int* __restrict__ csr_src,
                                                     const int* __restrict__ row_ptr,
                                                     const float* __restrict__ dinv,
                                                     const float* __restrict__ bias,
                                                     float* __restrict__ out, int n) {
    int node = blockIdx.x * 4 + threadIdx.y;
    if (node >= n) return;
    int lane = threadIdx.x;
    float2 acc = make_float2(0.f, 0.f);
    int e = row_ptr[node];
    int end = row_ptr[node + 1];
    for (; e + 8 <= end; e += 8) {
        int s[8]; float w[8]; unsigned int b[8];
#pragma unroll
        for (int j = 0; j < 8; ++j) s[j] = csr_src[e + j];
#pragma unroll
        for (int j = 0; j < 8; ++j) {
            w[j] = dinv[s[j]];
            b[j] = *(const unsigned int*)(H + (size_t)s[j] * 128 + lane * 2);
        }
#pragma unroll
        for (int j = 0; j < 8; ++j) {
            acc.x = fmaf(w[j], __uint_as_float(b[j] << 16), acc.x);
            acc.y = fmaf(w[j], __uint_as_float(b[j] & 0xFFFF0000u), acc.y);
        }
    }
    for (; e < end; ++e) {
        int s = csr_src[e];
        float w = dinv[s];
        unsigned int b = *(const unsigned int*)(H + (size_t)s * 128 + lane * 2);
        acc.x = fmaf(w, __uint_as_float(b << 16), acc.x);
        acc.y = fmaf(w, __uint_as_float(b & 0xFFFF0000u), acc.y);
    }
    float dn = dinv[node];
    unsigned int bn = *(const unsigned int*)(H + (size_t)node * 128 + lane * 2);
    acc.x = fmaf(dn, __uint_as_float(bn << 16), acc.x);
    acc.y = fmaf(dn, __uint_as_float(bn & 0xFFFF0000u), acc.y);
    float2 bb = *(const float2*)(bias + lane * 2);
    acc.x = fmaf(acc.x, dn, bb.x);
    acc.y = fmaf(acc.y, dn, bb.y);
    if (RELU) {
        acc.x = fmaxf(acc.x, 0.f);
        acc.y = fmaxf(acc.y, 0.f);
    }
    *(float2*)(out + (size_t)node * 128 + lane * 2) = acc;
}

// --- Aggregation D=64 (final layer, bf16 gather, fp32 out), x8 unroll.
__global__ __launch_bounds__(256) void agg64_kernel(const unsigned short* __restrict__ H,
                                                    const int* __restrict__ csr_src,
                                                    const int* __restrict__ row_ptr,
                                                    const float* __restrict__ dinv,
                                                    const float* __restrict__ bias,
                                                    float* __restrict__ out, int n) {
    int node = blockIdx.x * 4 + threadIdx.y;
    if (node >= n) return;
    int lane = threadIdx.x;
    float acc = 0.f;
    int e = row_ptr[node];
    int end = row_ptr[node + 1];
    for (; e + 8 <= end; e += 8) {
        int s[8]; float w[8]; unsigned short a[8];
#pragma unroll
        for (int j = 0; j < 8; ++j) s[j] = csr_src[e + j];
#pragma unroll
        for (int j = 0; j < 8; ++j) {
            w[j] = dinv[s[j]];
            a[j] = H[(size_t)s[j] * 64 + lane];
        }
#pragma unroll
        for (int j = 0; j < 8; ++j)
            acc = fmaf(w[j], __uint_as_float(((unsigned int)a[j]) << 16), acc);
    }
    for (; e < end; ++e) {
        int s = csr_src[e];
        acc = fmaf(dinv[s], __uint_as_float(((unsigned int)H[(size_t)s * 64 + lane]) << 16), acc);
    }
    float dn = dinv[node];
    acc = fmaf(dn, __uint_as_float(((unsigned int)H[(size_t)node * 64 + lane]) << 16), acc);
    acc = fmaf(acc, dn, bias[lane]);
    out[(size_t)node * 64 + lane] = acc;
}

extern "C" void kernel_launch(void* const* d_in, const int* in_sizes, int n_in,
                              void* d_out, int out_size, void* d_ws, size_t ws_size,
                              hipStream_t stream) {
    const float* x  = (const float*)d_in[0];
    const int*   ei = (const int*)d_in[1];
    const float* W1 = (const float*)d_in[2];
    const float* b1 = (const float*)d_in[3];
    const float* W2 = (const float*)d_in[4];
    const float* b2 = (const float*)d_in[5];
    const float* W3 = (const float*)d_in[6];
    const float* b3 = (const float*)d_in[7];

    const int n = in_sizes[0] / 128;   // 50000
    const int E = in_sizes[1] / 2;     // 1600000
    const int* src = ei;
    const int* dst = ei + E;
    const int nbkt = (n + 255) >> 8;           // 196
    const int NB = (E + EPB - 1) / EPB;        // 391

    char* ws = (char*)d_ws;
    size_t off = 0;
    auto alloc = [&](size_t bytes) {
        void* p = ws + off;
        off = (off + bytes + 511) & ~(size_t)511;
        return p;
    };
    int*   bucket_cnt  = (int*)alloc(256 * 4);
    int*   bucket_base = (int*)alloc(256 * 4);
    int*   row_ptr     = (int*)alloc((size_t)(n + 1) * 4);
    float* dinv        = (float*)alloc((size_t)n * 4);
    int*   csr_src     = (int*)alloc((size_t)E * 4);
    float* Fbuf        = (float*)alloc((size_t)n * 128 * 4);          // 25.6 MB (agg outs)
    unsigned short* Hb = (unsigned short*)alloc((size_t)n * 128 * 2); // 12.8 MB (GEMM outs)
    // pair_buf (NB*EPB int2 = 12.81MB) + dir (308KB) alias Fbuf: dead after
    // csr_kernel; Fbuf first written by agg1 (after csr_kernel completes).
    int2* pair_buf = (int2*)Fbuf;
    int*  dir      = (int*)((char*)Fbuf + (size_t)NB * EPB * 8);
    (void)ws_size;

    hipMemsetAsync(bucket_cnt, 0, 256 * 4, stream);

    bin_kernel<<<NB, 256, 0, stream>>>(src, dst, pair_buf, dir, bucket_cnt, E, nbkt);
    bucket_scan_kernel<<<1, 256, 0, stream>>>(bucket_cnt, bucket_base, nbkt);
    csr_kernel<<<nbkt, 512, 0, stream>>>(pair_buf, dir, bucket_base, row_ptr, dinv,
                                         csr_src, n, NB, nbkt);

    dim3 aggBlock(64, 4);
    int aggGrid = (n + 3) / 4;
    int gemmGrid = (n + 63) / 64;

    // layer 1
    gemm_bf16_kernel<128><<<gemmGrid, 256, 0, stream>>>(x, W1, Hb, n);
    agg128_kernel<true><<<aggGrid, aggBlock, 0, stream>>>(Hb, csr_src, row_ptr, dinv, b1, Fbuf, n);
    // layer 2
    gemm_bf16_kernel<128><<<gemmGrid, 256, 0, stream>>>(Fbuf, W2, Hb, n);
    agg128_kernel<true><<<aggGrid, aggBlock, 0, stream>>>(Hb, csr_src, row_ptr, dinv, b2, Fbuf, n);
    // layer 3 (64-wide, no relu)
    gemm_bf16_kernel<64><<<gemmGrid, 256, 0, stream>>>(Fbuf, W3, Hb, n);
    agg64_kernel<<<aggGrid, aggBlock, 0, stream>>>(Hb, csr_src, row_ptr, dinv, b3, (float*)d_out, n);
}

// Round 6
// 285.050 us; speedup vs baseline: 2.6530x; 1.0347x over previous
//
#include <hip/hip_runtime.h>
#include <type_traits>

// ---------------------------------------------------------------------------
// 3-layer GCN, all-bf16 H pipeline with dinv pre-scaling:
//   GEMM (MFMA bf16, fp32 accum) epilogue scales row r by dinv[r] -> H' bf16
//   agg: out[d] = dinv[d]*( sum_{e} H'[s] + H'[d] ) + b   (pure row-gather+add)
//   agg writes bf16 for layers 1,2 (next GEMM consumes bf16); fp32 for final.
// CSR build: bucketed sort with 32-bit packed pairs (src<<8 | dst&255).
// ---------------------------------------------------------------------------

#define EPB  4096   // edges per bin block
#define DIRW 197    // directory row width = max buckets (50176/256) + 1

typedef __attribute__((ext_vector_type(8))) short bf16x8;
typedef __attribute__((ext_vector_type(4))) float f32x4;

__device__ __forceinline__ unsigned short f2bf(float f) {
    unsigned int u = __float_as_uint(f);
    u += 0x7FFFu + ((u >> 16) & 1u);   // round-to-nearest-even
    return (unsigned short)(u >> 16);
}

// --- CSR build stage 1: per-block bucket sort, packed-pair dump + directory.
__global__ __launch_bounds__(256) void bin_kernel(const int* __restrict__ src,
                                                  const int* __restrict__ dst,
                                                  unsigned int* __restrict__ pair_buf,
                                                  int* __restrict__ dir,
                                                  int* __restrict__ bucket_cnt,
                                                  int E, int nbkt) {
    __shared__ unsigned int stage[EPB];  // 16 KB
    __shared__ int hist[DIRW];
    __shared__ int sc[256];
    __shared__ int cur[DIRW];
    int tid = threadIdx.x;
    int blk = blockIdx.x;
    if (tid < DIRW) hist[tid] = 0;
    __syncthreads();

    int s_reg[16], d_reg[16];
#pragma unroll
    for (int j = 0; j < 16; ++j) {
        int gi = blk * EPB + j * 256 + tid;
        int s = 0, d = nbkt << 8;          // invalid -> trash bucket nbkt
        if (gi < E) { s = src[gi]; d = dst[gi]; }
        s_reg[j] = s; d_reg[j] = d;
        atomicAdd(&hist[d >> 8], 1);
    }
    __syncthreads();
    int h = (tid < DIRW) ? hist[tid] : 0;
    sc[tid] = h;
    __syncthreads();
#pragma unroll
    for (int off = 1; off < 256; off <<= 1) {
        int v = (tid >= off) ? sc[tid - off] : 0;
        __syncthreads();
        sc[tid] += v;
        __syncthreads();
    }
    if (tid < DIRW) {
        int st = sc[tid] - h;
        cur[tid] = st;
        dir[blk * DIRW + tid] = st;
        if (tid < nbkt && h > 0) atomicAdd(&bucket_cnt[tid], h);
    }
    __syncthreads();
#pragma unroll
    for (int j = 0; j < 16; ++j) {
        int b = d_reg[j] >> 8;
        int slot = atomicAdd(&cur[b], 1);
        stage[slot] = ((unsigned int)s_reg[j] << 8) | (unsigned int)(d_reg[j] & 255);
    }
    __syncthreads();
#pragma unroll
    for (int j = 0; j < 16; ++j) {
        int idx = j * 256 + tid;
        pair_buf[blk * EPB + idx] = stage[idx];   // coalesced 4B dump
    }
}

// --- CSR build stage 2: exclusive scan of bucket counts -> bucket bases.
__global__ __launch_bounds__(256) void bucket_scan_kernel(const int* __restrict__ bucket_cnt,
                                                          int* __restrict__ bucket_base,
                                                          int nbkt) {
    __shared__ int sc[256];
    int tid = threadIdx.x;
    int h = (tid < nbkt) ? bucket_cnt[tid] : 0;
    sc[tid] = h;
    __syncthreads();
#pragma unroll
    for (int off = 1; off < 256; off <<= 1) {
        int v = (tid >= off) ? sc[tid - off] : 0;
        __syncthreads();
        sc[tid] += v;
        __syncthreads();
    }
    if (tid <= nbkt) bucket_base[tid] = sc[tid] - h;
}

// --- CSR build stage 3: one block per bucket (256 dsts).
__global__ __launch_bounds__(512) void csr_kernel(const unsigned int* __restrict__ pair_buf,
                                                  const int* __restrict__ dir,
                                                  const int* __restrict__ bucket_base,
                                                  int* __restrict__ row_ptr,
                                                  float* __restrict__ dinv,
                                                  int* __restrict__ csr_src,
                                                  int n, int NB, int nbkt) {
    __shared__ int dstart[400];
    __shared__ int dend[400];
    __shared__ int cnt[256];
    __shared__ int sc[256];
    __shared__ int cur[256];
    int tid = threadIdx.x;
    int b = blockIdx.x;
    for (int i = tid; i < NB; i += 512) {
        dstart[i] = dir[i * DIRW + b];
        dend[i]   = dir[i * DIRW + b + 1];
    }
    if (tid < 256) cnt[tid] = 0;
    __syncthreads();
    int wid = tid >> 6, lane = tid & 63;
    for (int seg = wid; seg < NB; seg += 8) {
        int s0 = dstart[seg], s1 = dend[seg];
        for (int k = s0 + lane; k < s1; k += 64) {
            unsigned int p = pair_buf[(size_t)seg * EPB + k];
            atomicAdd(&cnt[p & 255u], 1);
        }
    }
    __syncthreads();
    int c = (tid < 256) ? cnt[tid] : 0;
    if (tid < 256) sc[tid] = c;
    __syncthreads();
#pragma unroll
    for (int off = 1; off < 256; off <<= 1) {
        int v = 0;
        if (tid < 256 && tid >= off) v = sc[tid - off];
        __syncthreads();
        if (tid < 256) sc[tid] += v;
        __syncthreads();
    }
    int base = bucket_base[b];
    if (tid < 256) {
        int excl = sc[tid] - c;
        cur[tid] = excl;
        int d = b * 256 + tid;
        if (d < n) {
            row_ptr[d] = base + excl;
            dinv[d] = rsqrtf((float)(c + 1));   // +1 self loop
        }
    }
    if (b == 0 && tid == 0) row_ptr[n] = bucket_base[nbkt];
    __syncthreads();
    for (int seg = wid; seg < NB; seg += 8) {
        int s0 = dstart[seg], s1 = dend[seg];
        for (int k = s0 + lane; k < s1; k += 64) {
            unsigned int p = pair_buf[(size_t)seg * EPB + k];
            int pos = atomicAdd(&cur[p & 255u], 1);
            csr_src[base + pos] = (int)(p >> 8);
        }
    }
}

// --- MFMA bf16 GEMM + dinv row-scaling epilogue:
// H'[r][0..NOUT) = bf16( dinv[r] * (X[r][:] @ W[:][:]) )
// TA = float (layer 1) or unsigned short (bf16 input, layers 2/3).
template <int NOUT, typename TA>
__global__ __launch_bounds__(256) void gemm_bf16_kernel(const TA* __restrict__ X,
                                                        const float* __restrict__ W,
                                                        const float* __restrict__ dinv,
                                                        unsigned short* __restrict__ H,
                                                        int n_rows) {
    __shared__ short As[64][132];     // [m][k], 264B stride (8B-aligned)
    __shared__ short Bs[NOUT][132];   // [n][k]
    int tid = threadIdx.x;
    int row0 = blockIdx.x * 64;

    // stage A: 64 rows x 128 k; 4 threads/row, 32 cols each
    {
        int r = tid >> 2;
        int c0 = (tid & 3) * 32;
        int grow = row0 + r;
        if constexpr (std::is_same<TA, float>::value) {
            const float* xp = X + (size_t)grow * 128 + c0;
#pragma unroll
            for (int j = 0; j < 8; ++j) {
                float4 v = (grow < n_rows) ? *(const float4*)(xp + j * 4)
                                           : make_float4(0.f, 0.f, 0.f, 0.f);
                ushort4 p = { f2bf(v.x), f2bf(v.y), f2bf(v.z), f2bf(v.w) };
                *(ushort4*)&As[r][c0 + j * 4] = p;
            }
        } else {
            const unsigned short* xp = X + (size_t)grow * 128 + c0;
#pragma unroll
            for (int j = 0; j < 8; ++j) {
                uint2 v = (grow < n_rows) ? *(const uint2*)(xp + j * 4)
                                          : make_uint2(0u, 0u);
                *(uint2*)&As[r][c0 + j * 4] = v;
            }
        }
    }
    // stage B: W[128][NOUT] f32 -> Bs[n][k] bf16 (transposed scatter)
    {
        int k = tid >> 1;
        int nb = (tid & 1) * (NOUT / 2);
        const float* wp = W + (size_t)k * NOUT + nb;
#pragma unroll
        for (int j = 0; j < NOUT / 8; ++j) {
            float4 v = *(const float4*)(wp + j * 4);
            int nn = nb + j * 4;
            Bs[nn + 0][k] = (short)f2bf(v.x);
            Bs[nn + 1][k] = (short)f2bf(v.y);
            Bs[nn + 2][k] = (short)f2bf(v.z);
            Bs[nn + 3][k] = (short)f2bf(v.w);
        }
    }
    __syncthreads();

    int w = tid >> 6, l = tid & 63, lr = l & 15, lg = l >> 4;
    constexpr int NF = NOUT / 16;
    f32x4 acc[NF];
#pragma unroll
    for (int i = 0; i < NF; ++i) acc[i] = (f32x4){0.f, 0.f, 0.f, 0.f};
    int arow = w * 16 + lr;

#pragma unroll
    for (int kc = 0; kc < 128; kc += 32) {
        bf16x8 a;
        ((long long*)&a)[0] = *(const long long*)&As[arow][kc + lg * 4];
        ((long long*)&a)[1] = *(const long long*)&As[arow][kc + 16 + lg * 4];
#pragma unroll
        for (int nf = 0; nf < NF; ++nf) {
            bf16x8 b;
            ((long long*)&b)[0] = *(const long long*)&Bs[nf * 16 + lr][kc + lg * 4];
            ((long long*)&b)[1] = *(const long long*)&Bs[nf * 16 + lr][kc + 16 + lg * 4];
            acc[nf] = __builtin_amdgcn_mfma_f32_16x16x32_bf16(a, b, acc[nf], 0, 0, 0);
        }
    }
    int grow_base = row0 + w * 16 + lg * 4;
    float dv[4];
#pragma unroll
    for (int r = 0; r < 4; ++r)
        dv[r] = (grow_base + r < n_rows) ? dinv[grow_base + r] : 0.f;
#pragma unroll
    for (int nf = 0; nf < NF; ++nf) {
#pragma unroll
        for (int r = 0; r < 4; ++r) {
            int gr = grow_base + r;
            if (gr < n_rows) H[(size_t)gr * NOUT + nf * 16 + lr] = f2bf(acc[nf][r] * dv[r]);
        }
    }
}

// --- Aggregation D=128 on pre-scaled H' (bf16), x8 unroll; bf16 output.
// out[d] = relu( dinv[d]*( sum_e H'[s] + H'[d] ) + bias )
template <bool RELU>
__global__ __launch_bounds__(256) void agg128_kernel(const unsigned short* __restrict__ H,
                                                     const int* __restrict__ csr_src,
                                                     const int* __restrict__ row_ptr,
                                                     const float* __restrict__ dinv,
                                                     const float* __restrict__ bias,
                                                     unsigned short* __restrict__ out, int n) {
    int node = blockIdx.x * 4 + threadIdx.y;
    if (node >= n) return;
    int lane = threadIdx.x;
    float2 acc = make_float2(0.f, 0.f);
    int e = row_ptr[node];
    int end = row_ptr[node + 1];
    for (; e + 8 <= end; e += 8) {
        int s[8]; unsigned int b[8];
#pragma unroll
        for (int j = 0; j < 8; ++j) s[j] = csr_src[e + j];
#pragma unroll
        for (int j = 0; j < 8; ++j)
            b[j] = *(const unsigned int*)(H + (size_t)s[j] * 128 + lane * 2);
#pragma unroll
        for (int j = 0; j < 8; ++j) {
            acc.x += __uint_as_float(b[j] << 16);
            acc.y += __uint_as_float(b[j] & 0xFFFF0000u);
        }
    }
    for (; e < end; ++e) {
        int s = csr_src[e];
        unsigned int b = *(const unsigned int*)(H + (size_t)s * 128 + lane * 2);
        acc.x += __uint_as_float(b << 16);
        acc.y += __uint_as_float(b & 0xFFFF0000u);
    }
    // self loop (H' already scaled by dinv[node])
    unsigned int bn = *(const unsigned int*)(H + (size_t)node * 128 + lane * 2);
    acc.x += __uint_as_float(bn << 16);
    acc.y += __uint_as_float(bn & 0xFFFF0000u);
    float dn = dinv[node];
    float2 bb = *(const float2*)(bias + lane * 2);
    acc.x = fmaf(acc.x, dn, bb.x);
    acc.y = fmaf(acc.y, dn, bb.y);
    if (RELU) {
        acc.x = fmaxf(acc.x, 0.f);
        acc.y = fmaxf(acc.y, 0.f);
    }
    unsigned int pk = ((unsigned int)f2bf(acc.y) << 16) | (unsigned int)f2bf(acc.x);
    *(unsigned int*)(out + (size_t)node * 128 + lane * 2) = pk;
}

// --- Aggregation D=64 (final layer): pre-scaled bf16 H', fp32 out, no relu.
__global__ __launch_bounds__(256) void agg64_kernel(const unsigned short* __restrict__ H,
                                                    const int* __restrict__ csr_src,
                                                    const int* __restrict__ row_ptr,
                                                    const float* __restrict__ dinv,
                                                    const float* __restrict__ bias,
                                                    float* __restrict__ out, int n) {
    int node = blockIdx.x * 4 + threadIdx.y;
    if (node >= n) return;
    int lane = threadIdx.x;
    float acc = 0.f;
    int e = row_ptr[node];
    int end = row_ptr[node + 1];
    for (; e + 8 <= end; e += 8) {
        int s[8]; unsigned short a[8];
#pragma unroll
        for (int j = 0; j < 8; ++j) s[j] = csr_src[e + j];
#pragma unroll
        for (int j = 0; j < 8; ++j) a[j] = H[(size_t)s[j] * 64 + lane];
#pragma unroll
        for (int j = 0; j < 8; ++j)
            acc += __uint_as_float(((unsigned int)a[j]) << 16);
    }
    for (; e < end; ++e) {
        int s = csr_src[e];
        acc += __uint_as_float(((unsigned int)H[(size_t)s * 64 + lane]) << 16);
    }
    acc += __uint_as_float(((unsigned int)H[(size_t)node * 64 + lane]) << 16);
    acc = fmaf(acc, dinv[node], bias[lane]);
    out[(size_t)node * 64 + lane] = acc;
}

extern "C" void kernel_launch(void* const* d_in, const int* in_sizes, int n_in,
                              void* d_out, int out_size, void* d_ws, size_t ws_size,
                              hipStream_t stream) {
    const float* x  = (const float*)d_in[0];
    const int*   ei = (const int*)d_in[1];
    const float* W1 = (const float*)d_in[2];
    const float* b1 = (const float*)d_in[3];
    const float* W2 = (const float*)d_in[4];
    const float* b2 = (const float*)d_in[5];
    const float* W3 = (const float*)d_in[6];
    const float* b3 = (const float*)d_in[7];

    const int n = in_sizes[0] / 128;   // 50000
    const int E = in_sizes[1] / 2;     // 1600000
    const int* src = ei;
    const int* dst = ei + E;
    const int nbkt = (n + 255) >> 8;           // 196
    const int NB = (E + EPB - 1) / EPB;        // 391

    char* ws = (char*)d_ws;
    size_t off = 0;
    auto alloc = [&](size_t bytes) {
        void* p = ws + off;
        off = (off + bytes + 511) & ~(size_t)511;
        return p;
    };
    int*   bucket_cnt  = (int*)alloc(256 * 4);
    int*   bucket_base = (int*)alloc(256 * 4);
    int*   row_ptr     = (int*)alloc((size_t)(n + 1) * 4);
    float* dinv        = (float*)alloc((size_t)n * 4);
    int*   csr_src     = (int*)alloc((size_t)E * 4);
    unsigned short* Hb = (unsigned short*)alloc((size_t)n * 128 * 2); // GEMM outs (pre-scaled)
    unsigned short* Bb = (unsigned short*)alloc((size_t)n * 128 * 2); // agg outs (bf16)
    // pair_buf (NB*EPB uint = 6.4MB) + dir (308KB) alias Bb: dead after
    // csr_kernel; Bb first written by agg1 (after csr_kernel completes).
    unsigned int* pair_buf = (unsigned int*)Bb;
    int*          dir      = (int*)((char*)Bb + (size_t)NB * EPB * 4);
    (void)ws_size;

    hipMemsetAsync(bucket_cnt, 0, 256 * 4, stream);

    bin_kernel<<<NB, 256, 0, stream>>>(src, dst, pair_buf, dir, bucket_cnt, E, nbkt);
    bucket_scan_kernel<<<1, 256, 0, stream>>>(bucket_cnt, bucket_base, nbkt);
    csr_kernel<<<nbkt, 512, 0, stream>>>(pair_buf, dir, bucket_base, row_ptr, dinv,
                                         csr_src, n, NB, nbkt);

    dim3 aggBlock(64, 4);
    int aggGrid = (n + 3) / 4;
    int gemmGrid = (n + 63) / 64;

    // layer 1
    gemm_bf16_kernel<128, float><<<gemmGrid, 256, 0, stream>>>(x, W1, dinv, Hb, n);
    agg128_kernel<true><<<aggGrid, aggBlock, 0, stream>>>(Hb, csr_src, row_ptr, dinv, b1, Bb, n);
    // layer 2
    gemm_bf16_kernel<128, unsigned short><<<gemmGrid, 256, 0, stream>>>(Bb, W2, dinv, Hb, n);
    agg128_kernel<true><<<aggGrid, aggBlock, 0, stream>>>(Hb, csr_src, row_ptr, dinv, b2, Bb, n);
    // layer 3 (64-wide, no relu)
    gemm_bf16_kernel<64, unsigned short><<<gemmGrid, 256, 0, stream>>>(Bb, W3, dinv, Hb, n);
    agg64_kernel<<<aggGrid, aggBlock, 0, stream>>>(Hb, csr_src, row_ptr, dinv, b3, (float*)d_out, n);
}

// Round 7
// 260.192 us; speedup vs baseline: 2.9065x; 1.0955x over previous
//
#include <hip/hip_runtime.h>
#include <type_traits>

// ---------------------------------------------------------------------------
// 3-layer GCN, all-bf16 H pipeline with dinv pre-scaling:
//   GEMM (MFMA bf16, fp32 accum) epilogue scales row r by dinv[r] -> H' bf16
//   agg: out[d] = dinv[d]*( sum_e H'[s] + H'[d] ) + b
// Aggregation: 4 nodes per wave (16 lanes x uint4 per 256B row). CSR slots are
// padded per 4-node group to uniform multiple-of-8 length; pad entries point
// to row n of H, which is zeroed (L1-hot, free) -> zero divergence, x8 unroll.
// CSR build: bin (bucket sort by dst>>8) -> sizes (padded totals) -> scan ->
// place (+pad fill). All placement deterministic.
// ---------------------------------------------------------------------------

#define EPB  4096   // edges per bin block
#define DIRW 197    // directory row width = max buckets (50176/256) + 1

typedef __attribute__((ext_vector_type(8))) short bf16x8;
typedef __attribute__((ext_vector_type(4))) float f32x4;

__device__ __forceinline__ unsigned short f2bf(float f) {
    unsigned int u = __float_as_uint(f);
    u += 0x7FFFu + ((u >> 16) & 1u);   // round-to-nearest-even
    return (unsigned short)(u >> 16);
}
__device__ __forceinline__ float bflo(unsigned int u) { return __uint_as_float(u << 16); }
__device__ __forceinline__ float bfhi(unsigned int u) { return __uint_as_float(u & 0xFFFF0000u); }

// --- CSR stage 1: per-block bucket sort, packed-pair dump + directory.
__global__ __launch_bounds__(256) void bin_kernel(const int* __restrict__ src,
                                                  const int* __restrict__ dst,
                                                  unsigned int* __restrict__ pair_buf,
                                                  int* __restrict__ dir,
                                                  int E, int nbkt) {
    __shared__ unsigned int stage[EPB];  // 16 KB
    __shared__ int hist[DIRW];
    __shared__ int sc[256];
    __shared__ int cur[DIRW];
    int tid = threadIdx.x;
    int blk = blockIdx.x;
    if (tid < DIRW) hist[tid] = 0;
    __syncthreads();

    int s_reg[16], d_reg[16];
#pragma unroll
    for (int j = 0; j < 16; ++j) {
        int gi = blk * EPB + j * 256 + tid;
        int s = 0, d = nbkt << 8;          // invalid -> trash bucket nbkt
        if (gi < E) { s = src[gi]; d = dst[gi]; }
        s_reg[j] = s; d_reg[j] = d;
        atomicAdd(&hist[d >> 8], 1);
    }
    __syncthreads();
    int h = (tid < DIRW) ? hist[tid] : 0;
    sc[tid] = h;
    __syncthreads();
#pragma unroll
    for (int off = 1; off < 256; off <<= 1) {
        int v = (tid >= off) ? sc[tid - off] : 0;
        __syncthreads();
        sc[tid] += v;
        __syncthreads();
    }
    if (tid < DIRW) {
        int st = sc[tid] - h;
        cur[tid] = st;
        dir[blk * DIRW + tid] = st;
    }
    __syncthreads();
#pragma unroll
    for (int j = 0; j < 16; ++j) {
        int b = d_reg[j] >> 8;
        int slot = atomicAdd(&cur[b], 1);
        stage[slot] = ((unsigned int)s_reg[j] << 8) | (unsigned int)(d_reg[j] & 255);
    }
    __syncthreads();
#pragma unroll
    for (int j = 0; j < 16; ++j) {
        int idx = j * 256 + tid;
        pair_buf[blk * EPB + idx] = stage[idx];   // coalesced 4B dump
    }
}

// --- CSR stage 2: per-bucket padded total (groups of 4 nodes, align8(max)).
__global__ __launch_bounds__(512) void csr_sizes_kernel(const unsigned int* __restrict__ pair_buf,
                                                        const int* __restrict__ dir,
                                                        int* __restrict__ bucket_pad,
                                                        int NB) {
    __shared__ int dstart[400];
    __shared__ int dend[400];
    __shared__ int cnt[256];
    int tid = threadIdx.x;
    int b = blockIdx.x;
    for (int i = tid; i < NB; i += 512) {
        dstart[i] = dir[i * DIRW + b];
        dend[i]   = dir[i * DIRW + b + 1];
    }
    if (tid < 256) cnt[tid] = 0;
    __syncthreads();
    int wid = tid >> 6, lane = tid & 63;
    for (int seg = wid; seg < NB; seg += 8) {
        int s0 = dstart[seg], s1 = dend[seg];
        for (int k = s0 + lane; k < s1; k += 64) {
            unsigned int p = pair_buf[(size_t)seg * EPB + k];
            atomicAdd(&cnt[p & 255u], 1);
        }
    }
    __syncthreads();
    if (tid < 64) {
        int m = max(max(cnt[4 * tid], cnt[4 * tid + 1]),
                    max(cnt[4 * tid + 2], cnt[4 * tid + 3]));
        int L = (m + 7) & ~7;
        int s = L;
#pragma unroll
        for (int off = 1; off < 64; off <<= 1) s += __shfl_xor(s, off);
        if (tid == 0) bucket_pad[b] = 4 * s;
    }
}

// --- CSR stage 3: exclusive scan of padded bucket totals -> bases; row_ptr[n].
__global__ __launch_bounds__(256) void bucket_scan_kernel(const int* __restrict__ bucket_pad,
                                                          int* __restrict__ bucket_base,
                                                          int* __restrict__ row_ptr,
                                                          int nbkt, int n) {
    __shared__ int sc[256];
    int tid = threadIdx.x;
    int h = (tid < nbkt) ? bucket_pad[tid] : 0;
    sc[tid] = h;
    __syncthreads();
#pragma unroll
    for (int off = 1; off < 256; off <<= 1) {
        int v = (tid >= off) ? sc[tid - off] : 0;
        __syncthreads();
        sc[tid] += v;
        __syncthreads();
    }
    if (tid <= nbkt) bucket_base[tid] = sc[tid] - h;
    if (tid == nbkt) row_ptr[n] = sc[tid] - h;   // total (h=0 at tid==nbkt)
}

// --- CSR stage 4: place into padded slots; fill pads with index n (zero row).
__global__ __launch_bounds__(512) void csr_place_kernel(const unsigned int* __restrict__ pair_buf,
                                                        const int* __restrict__ dir,
                                                        const int* __restrict__ bucket_base,
                                                        int* __restrict__ row_ptr,
                                                        float* __restrict__ dinv,
                                                        int* __restrict__ csr_src,
                                                        int n, int NB) {
    __shared__ int dstart[400];
    __shared__ int dend[400];
    __shared__ int cnt[256];
    __shared__ int Lg[64];
    __shared__ int Lpre[64];
    __shared__ int nbase[256];
    __shared__ int cur[256];
    int tid = threadIdx.x;
    int b = blockIdx.x;
    for (int i = tid; i < NB; i += 512) {
        dstart[i] = dir[i * DIRW + b];
        dend[i]   = dir[i * DIRW + b + 1];
    }
    if (tid < 256) cnt[tid] = 0;
    __syncthreads();
    int wid = tid >> 6, lane = tid & 63;
    for (int seg = wid; seg < NB; seg += 8) {
        int s0 = dstart[seg], s1 = dend[seg];
        for (int k = s0 + lane; k < s1; k += 64) {
            unsigned int p = pair_buf[(size_t)seg * EPB + k];
            atomicAdd(&cnt[p & 255u], 1);
        }
    }
    __syncthreads();
    if (tid < 64) {
        int m = max(max(cnt[4 * tid], cnt[4 * tid + 1]),
                    max(cnt[4 * tid + 2], cnt[4 * tid + 3]));
        int L = (m + 7) & ~7;
        int x = L;
#pragma unroll
        for (int off = 1; off < 64; off <<= 1) {
            int y = __shfl_up(x, off);
            if (tid >= off) x += y;
        }
        Lg[tid] = L;
        Lpre[tid] = x - L;
    }
    __syncthreads();
    int base = bucket_base[b];
    if (tid < 256) {
        int g = tid >> 2;
        int nb = base + 4 * Lpre[g] + (tid & 3) * Lg[g];
        nbase[tid] = nb;
        cur[tid] = nb;
        int d = b * 256 + tid;
        if (d < n) {
            row_ptr[d] = nb;
            dinv[d] = rsqrtf((float)(cnt[tid] + 1));   // +1 self loop
        }
    }
    __syncthreads();
    for (int seg = wid; seg < NB; seg += 8) {
        int s0 = dstart[seg], s1 = dend[seg];
        for (int k = s0 + lane; k < s1; k += 64) {
            unsigned int p = pair_buf[(size_t)seg * EPB + k];
            int pos = atomicAdd(&cur[p & 255u], 1);
            csr_src[pos] = (int)(p >> 8);
        }
    }
    __syncthreads();
    if (tid < 256) {
        int endp = nbase[tid] + Lg[tid >> 2];
        for (int pos = cur[tid]; pos < endp; ++pos) csr_src[pos] = n;  // pad -> zero row
    }
}

// --- MFMA bf16 GEMM + dinv row-scaling epilogue:
// H'[r][0..NOUT) = bf16( dinv[r] * (X[r][:] @ W[:][:]) )
template <int NOUT, typename TA>
__global__ __launch_bounds__(256) void gemm_bf16_kernel(const TA* __restrict__ X,
                                                        const float* __restrict__ W,
                                                        const float* __restrict__ dinv,
                                                        unsigned short* __restrict__ H,
                                                        int n_rows) {
    __shared__ short As[64][132];     // [m][k], 264B stride (8B-aligned)
    __shared__ short Bs[NOUT][132];   // [n][k]
    int tid = threadIdx.x;
    int row0 = blockIdx.x * 64;

    {
        int r = tid >> 2;
        int c0 = (tid & 3) * 32;
        int grow = row0 + r;
        if constexpr (std::is_same<TA, float>::value) {
            const float* xp = X + (size_t)grow * 128 + c0;
#pragma unroll
            for (int j = 0; j < 8; ++j) {
                float4 v = (grow < n_rows) ? *(const float4*)(xp + j * 4)
                                           : make_float4(0.f, 0.f, 0.f, 0.f);
                ushort4 p = { f2bf(v.x), f2bf(v.y), f2bf(v.z), f2bf(v.w) };
                *(ushort4*)&As[r][c0 + j * 4] = p;
            }
        } else {
            const unsigned short* xp = X + (size_t)grow * 128 + c0;
#pragma unroll
            for (int j = 0; j < 8; ++j) {
                uint2 v = (grow < n_rows) ? *(const uint2*)(xp + j * 4)
                                          : make_uint2(0u, 0u);
                *(uint2*)&As[r][c0 + j * 4] = v;
            }
        }
    }
    {
        int k = tid >> 1;
        int nb = (tid & 1) * (NOUT / 2);
        const float* wp = W + (size_t)k * NOUT + nb;
#pragma unroll
        for (int j = 0; j < NOUT / 8; ++j) {
            float4 v = *(const float4*)(wp + j * 4);
            int nn = nb + j * 4;
            Bs[nn + 0][k] = (short)f2bf(v.x);
            Bs[nn + 1][k] = (short)f2bf(v.y);
            Bs[nn + 2][k] = (short)f2bf(v.z);
            Bs[nn + 3][k] = (short)f2bf(v.w);
        }
    }
    __syncthreads();

    int w = tid >> 6, l = tid & 63, lr = l & 15, lg = l >> 4;
    constexpr int NF = NOUT / 16;
    f32x4 acc[NF];
#pragma unroll
    for (int i = 0; i < NF; ++i) acc[i] = (f32x4){0.f, 0.f, 0.f, 0.f};
    int arow = w * 16 + lr;

#pragma unroll
    for (int kc = 0; kc < 128; kc += 32) {
        bf16x8 a;
        ((long long*)&a)[0] = *(const long long*)&As[arow][kc + lg * 4];
        ((long long*)&a)[1] = *(const long long*)&As[arow][kc + 16 + lg * 4];
#pragma unroll
        for (int nf = 0; nf < NF; ++nf) {
            bf16x8 b;
            ((long long*)&b)[0] = *(const long long*)&Bs[nf * 16 + lr][kc + lg * 4];
            ((long long*)&b)[1] = *(const long long*)&Bs[nf * 16 + lr][kc + 16 + lg * 4];
            acc[nf] = __builtin_amdgcn_mfma_f32_16x16x32_bf16(a, b, acc[nf], 0, 0, 0);
        }
    }
    int grow_base = row0 + w * 16 + lg * 4;
    float dv[4];
#pragma unroll
    for (int r = 0; r < 4; ++r)
        dv[r] = (grow_base + r < n_rows) ? dinv[grow_base + r] : 0.f;
#pragma unroll
    for (int nf = 0; nf < NF; ++nf) {
#pragma unroll
        for (int r = 0; r < 4; ++r) {
            int gr = grow_base + r;
            if (gr < n_rows) H[(size_t)gr * NOUT + nf * 16 + lr] = f2bf(acc[nf][r] * dv[r]);
        }
    }
}

// --- Aggregation D=128: 4 nodes/wave, 16 lanes x uint4 per 256B row, x8 unroll.
// Uniform padded slot length per group -> no divergence; pads hit zero row n.
template <bool RELU>
__global__ __launch_bounds__(256) void agg128_kernel(const unsigned short* __restrict__ H,
                                                     const int* __restrict__ csr_src,
                                                     const int* __restrict__ row_ptr,
                                                     const float* __restrict__ dinv,
                                                     const float* __restrict__ bias,
                                                     unsigned short* __restrict__ out, int n) {
    int g = blockIdx.x * 4 + threadIdx.y;
    int node0 = g * 4;
    if (node0 >= n) return;
    int lane = threadIdx.x;
    int sub = lane >> 4, l16 = lane & 15;
    int node = node0 + sub;
    int base = row_ptr[node0];
    int L = (row_ptr[node0 + 4] - base) >> 2;
    int e0 = base + sub * L;
    const uint4* H4 = (const uint4*)H;
    float acc[8] = {0.f, 0.f, 0.f, 0.f, 0.f, 0.f, 0.f, 0.f};
    for (int k = 0; k < L; k += 8) {
        int idx[8];
#pragma unroll
        for (int j = 0; j < 8; ++j) idx[j] = csr_src[e0 + k + j];
        uint4 v[8];
#pragma unroll
        for (int j = 0; j < 8; ++j) v[j] = H4[(size_t)idx[j] * 16 + l16];
#pragma unroll
        for (int j = 0; j < 8; ++j) {
            acc[0] += bflo(v[j].x); acc[1] += bfhi(v[j].x);
            acc[2] += bflo(v[j].y); acc[3] += bfhi(v[j].y);
            acc[4] += bflo(v[j].z); acc[5] += bfhi(v[j].z);
            acc[6] += bflo(v[j].w); acc[7] += bfhi(v[j].w);
        }
    }
    // self loop (H' already scaled by dinv[node])
    uint4 vn = H4[(size_t)node * 16 + l16];
    acc[0] += bflo(vn.x); acc[1] += bfhi(vn.x);
    acc[2] += bflo(vn.y); acc[3] += bfhi(vn.y);
    acc[4] += bflo(vn.z); acc[5] += bfhi(vn.z);
    acc[6] += bflo(vn.w); acc[7] += bfhi(vn.w);
    float dn = dinv[node];
    const float4* b4 = (const float4*)(bias + l16 * 8);
    float4 bb0 = b4[0], bb1 = b4[1];
    float r0 = fmaf(acc[0], dn, bb0.x), r1 = fmaf(acc[1], dn, bb0.y);
    float r2 = fmaf(acc[2], dn, bb0.z), r3 = fmaf(acc[3], dn, bb0.w);
    float r4 = fmaf(acc[4], dn, bb1.x), r5 = fmaf(acc[5], dn, bb1.y);
    float r6 = fmaf(acc[6], dn, bb1.z), r7 = fmaf(acc[7], dn, bb1.w);
    if (RELU) {
        r0 = fmaxf(r0, 0.f); r1 = fmaxf(r1, 0.f); r2 = fmaxf(r2, 0.f); r3 = fmaxf(r3, 0.f);
        r4 = fmaxf(r4, 0.f); r5 = fmaxf(r5, 0.f); r6 = fmaxf(r6, 0.f); r7 = fmaxf(r7, 0.f);
    }
    uint4 pk;
    pk.x = ((unsigned int)f2bf(r1) << 16) | (unsigned int)f2bf(r0);
    pk.y = ((unsigned int)f2bf(r3) << 16) | (unsigned int)f2bf(r2);
    pk.z = ((unsigned int)f2bf(r5) << 16) | (unsigned int)f2bf(r4);
    pk.w = ((unsigned int)f2bf(r7) << 16) | (unsigned int)f2bf(r6);
    ((uint4*)out)[(size_t)node * 16 + l16] = pk;
}

// --- Aggregation D=64 (final): 4 nodes/wave, 16 lanes x uint2, fp32 out.
__global__ __launch_bounds__(256) void agg64_kernel(const unsigned short* __restrict__ H,
                                                    const int* __restrict__ csr_src,
                                                    const int* __restrict__ row_ptr,
                                                    const float* __restrict__ dinv,
                                                    const float* __restrict__ bias,
                                                    float* __restrict__ out, int n) {
    int g = blockIdx.x * 4 + threadIdx.y;
    int node0 = g * 4;
    if (node0 >= n) return;
    int lane = threadIdx.x;
    int sub = lane >> 4, l16 = lane & 15;
    int node = node0 + sub;
    int base = row_ptr[node0];
    int L = (row_ptr[node0 + 4] - base) >> 2;
    int e0 = base + sub * L;
    const uint2* H2 = (const uint2*)H;
    float acc[4] = {0.f, 0.f, 0.f, 0.f};
    for (int k = 0; k < L; k += 8) {
        int idx[8];
#pragma unroll
        for (int j = 0; j < 8; ++j) idx[j] = csr_src[e0 + k + j];
        uint2 v[8];
#pragma unroll
        for (int j = 0; j < 8; ++j) v[j] = H2[(size_t)idx[j] * 16 + l16];
#pragma unroll
        for (int j = 0; j < 8; ++j) {
            acc[0] += bflo(v[j].x); acc[1] += bfhi(v[j].x);
            acc[2] += bflo(v[j].y); acc[3] += bfhi(v[j].y);
        }
    }
    uint2 vn = H2[(size_t)node * 16 + l16];
    acc[0] += bflo(vn.x); acc[1] += bfhi(vn.x);
    acc[2] += bflo(vn.y); acc[3] += bfhi(vn.y);
    float dn = dinv[node];
    float4 bb = *(const float4*)(bias + l16 * 4);
    float4 r;
    r.x = fmaf(acc[0], dn, bb.x);
    r.y = fmaf(acc[1], dn, bb.y);
    r.z = fmaf(acc[2], dn, bb.z);
    r.w = fmaf(acc[3], dn, bb.w);
    *(float4*)(out + (size_t)node * 64 + l16 * 4) = r;
}

extern "C" void kernel_launch(void* const* d_in, const int* in_sizes, int n_in,
                              void* d_out, int out_size, void* d_ws, size_t ws_size,
                              hipStream_t stream) {
    const float* x  = (const float*)d_in[0];
    const int*   ei = (const int*)d_in[1];
    const float* W1 = (const float*)d_in[2];
    const float* b1 = (const float*)d_in[3];
    const float* W2 = (const float*)d_in[4];
    const float* b2 = (const float*)d_in[5];
    const float* W3 = (const float*)d_in[6];
    const float* b3 = (const float*)d_in[7];

    const int n = in_sizes[0] / 128;   // 50000 (divisible by 4)
    const int E = in_sizes[1] / 2;     // 1600000
    const int* src = ei;
    const int* dst = ei + E;
    const int nbkt = (n + 255) >> 8;           // 196
    const int NB = (E + EPB - 1) / EPB;        // 391

    char* ws = (char*)d_ws;
    size_t off = 0;
    auto alloc = [&](size_t bytes) {
        void* p = ws + off;
        off = (off + bytes + 511) & ~(size_t)511;
        return p;
    };
    int*   bucket_pad  = (int*)alloc(256 * 4);
    int*   bucket_base = (int*)alloc(512 * 4);
    int*   row_ptr     = (int*)alloc((size_t)(n + 1) * 4);
    float* dinv        = (float*)alloc((size_t)n * 4);
    int*   csr_src     = (int*)alloc((size_t)4000000 * 4);              // padded CSR (~2.1M used)
    unsigned short* Hb = (unsigned short*)alloc((size_t)(n + 1) * 128 * 2); // +1 zero pad row
    unsigned short* Bb = (unsigned short*)alloc((size_t)n * 128 * 2);
    // pair_buf (NB*EPB uint = 6.4MB) + dir (308KB) alias Bb: dead after
    // csr_place; Bb first written by agg1 (after csr_place completes).
    unsigned int* pair_buf = (unsigned int*)Bb;
    int*          dir      = (int*)((char*)Bb + (size_t)NB * EPB * 4);
    (void)ws_size;

    bin_kernel<<<NB, 256, 0, stream>>>(src, dst, pair_buf, dir, E, nbkt);
    csr_sizes_kernel<<<nbkt, 512, 0, stream>>>(pair_buf, dir, bucket_pad, NB);
    bucket_scan_kernel<<<1, 256, 0, stream>>>(bucket_pad, bucket_base, row_ptr, nbkt, n);
    csr_place_kernel<<<nbkt, 512, 0, stream>>>(pair_buf, dir, bucket_base, row_ptr, dinv,
                                               csr_src, n, NB);
    // zero pad row n (128-wide layout) before aggs use it
    hipMemsetAsync(Hb + (size_t)n * 128, 0, 256, stream);

    dim3 aggBlock(64, 4);
    int aggGrid = (n / 4 + 3) / 4;     // 4 nodes/wave, 4 waves/block
    int gemmGrid = (n + 63) / 64;

    // layer 1
    gemm_bf16_kernel<128, float><<<gemmGrid, 256, 0, stream>>>(x, W1, dinv, Hb, n);
    agg128_kernel<true><<<aggGrid, aggBlock, 0, stream>>>(Hb, csr_src, row_ptr, dinv, b1, Bb, n);
    // layer 2
    gemm_bf16_kernel<128, unsigned short><<<gemmGrid, 256, 0, stream>>>(Bb, W2, dinv, Hb, n);
    agg128_kernel<true><<<aggGrid, aggBlock, 0, stream>>>(Hb, csr_src, row_ptr, dinv, b2, Bb, n);
    // layer 3 (64-wide): zero pad row in 64-wide layout, then gemm+agg
    hipMemsetAsync(Hb + (size_t)n * 64, 0, 128, stream);
    gemm_bf16_kernel<64, unsigned short><<<gemmGrid, 256, 0, stream>>>(Bb, W3, dinv, Hb, n);
    agg64_kernel<<<aggGrid, aggBlock, 0, stream>>>(Hb, csr_src, row_ptr, dinv, b3, (float*)d_out, n);
}